// Round 1
// baseline (1637.362 us; speedup 1.0000x reference)
//
#include <hip/hip_runtime.h>

#define D_HID 128

// ---------------- CSR build ----------------

__global__ __launch_bounds__(256) void k_count(const int* __restrict__ ei, int* __restrict__ cnt, int E) {
    int e = blockIdx.x * 256 + threadIdx.x;
    if (e < E) atomicAdd(&cnt[ei[E + e]], 1);
}

__global__ __launch_bounds__(256) void k_scan1(const int* __restrict__ cnt, int* __restrict__ row_ptr,
                                               int* __restrict__ blockSums, int n) {
    __shared__ int sdata[256];
    int tid = threadIdx.x;
    int base = blockIdx.x * 1024 + tid * 4;
    int v0 = (base + 0 < n) ? cnt[base + 0] : 0;
    int v1 = (base + 1 < n) ? cnt[base + 1] : 0;
    int v2 = (base + 2 < n) ? cnt[base + 2] : 0;
    int v3 = (base + 3 < n) ? cnt[base + 3] : 0;
    int t = v0 + v1 + v2 + v3;
    int x = t;
    sdata[tid] = x; __syncthreads();
    for (int off = 1; off < 256; off <<= 1) {
        int y = (tid >= off) ? sdata[tid - off] : 0;
        __syncthreads();
        x += y;
        sdata[tid] = x;
        __syncthreads();
    }
    int p = x - t;  // exclusive prefix within block
    if (base + 0 < n) row_ptr[base + 0] = p;
    if (base + 1 < n) row_ptr[base + 1] = p + v0;
    if (base + 2 < n) row_ptr[base + 2] = p + v0 + v1;
    if (base + 3 < n) row_ptr[base + 3] = p + v0 + v1 + v2;
    if (tid == 255) blockSums[blockIdx.x] = x;
}

__global__ __launch_bounds__(128) void k_scan2(const int* __restrict__ blockSums, int* __restrict__ blockOffs, int nb) {
    __shared__ int sdata[128];
    int tid = threadIdx.x;
    int t = (tid < nb) ? blockSums[tid] : 0;
    int x = t;
    sdata[tid] = x; __syncthreads();
    for (int off = 1; off < 128; off <<= 1) {
        int y = (tid >= off) ? sdata[tid - off] : 0;
        __syncthreads();
        x += y;
        sdata[tid] = x;
        __syncthreads();
    }
    blockOffs[tid] = x - t;  // exclusive
}

__global__ __launch_bounds__(256) void k_scan3(int* __restrict__ row_ptr, const int* __restrict__ blockOffs, int n) {
    int add = blockOffs[blockIdx.x];
    int base = blockIdx.x * 1024 + threadIdx.x * 4;
    if (base + 0 < n) row_ptr[base + 0] += add;
    if (base + 1 < n) row_ptr[base + 1] += add;
    if (base + 2 < n) row_ptr[base + 2] += add;
    if (base + 3 < n) row_ptr[base + 3] += add;
}

__global__ __launch_bounds__(256) void k_fill(const int* __restrict__ ei, const float* __restrict__ ea,
                                              const int* __restrict__ row_ptr, int* __restrict__ fillpos,
                                              int* __restrict__ csr_src, float* __restrict__ agg_e, int E) {
    int e = blockIdx.x * 256 + threadIdx.x;
    if (e >= E) return;
    int s = ei[e];
    int d = ei[E + e];
    int p = atomicAdd(&fillpos[d], 1);
    csr_src[row_ptr[d] + p] = s;
    float4 a = ((const float4*)ea)[e];
    atomicAdd(&agg_e[d * 4 + 0], a.x);
    atomicAdd(&agg_e[d * 4 + 1], a.y);
    atomicAdd(&agg_e[d * 4 + 2], a.z);
    atomicAdd(&agg_e[d * 4 + 3], a.w);
}

// ---------------- per-layer: gather aggregation ----------------
// agg[v] = x[v] (self loop) + sum over incoming edges of x[src]
__global__ __launch_bounds__(256) void k_gather(const float* __restrict__ xin, float* __restrict__ agg,
                                                const int* __restrict__ row_ptr, const int* __restrict__ cnt,
                                                const int* __restrict__ csr_src, int n) {
    int wid = (blockIdx.x * 256 + threadIdx.x) >> 6;
    int lane = threadIdx.x & 63;
    if (wid >= n) return;
    const float2* x2 = (const float2*)xin;
    float2 acc = x2[(size_t)wid * 64 + lane];  // self loop
    int start = row_ptr[wid];
    int deg = cnt[wid];
    for (int base = 0; base < deg; base += 64) {
        int idx = 0;
        if (base + lane < deg) idx = csr_src[start + base + lane];
        int m = deg - base; if (m > 64) m = 64;
        for (int i = 0; i < m; ++i) {
            int s = __shfl(idx, i);
            float2 xv = x2[(size_t)s * 64 + lane];
            acc.x += xv.x; acc.y += xv.y;
        }
    }
    ((float2*)agg)[(size_t)wid * 64 + lane] = acc;
}

// ---------------- per-layer: GEMM + edge-bias + bias + relu, in-place ----------------
// x[v,:] = relu( agg_x[v,:] @ W[0:128,:] + agg_e[v,:] @ W[128:132,:] + b )
__global__ __launch_bounds__(256) void k_gemm(float* __restrict__ x, const float* __restrict__ agg_e,
                                              const float* __restrict__ W, const float* __restrict__ bias, int n) {
    __shared__ float wLDS[32 * 128];   // 16KB: W k-chunk
    __shared__ float aLDS[64 * 33];    // 8.4KB: A tile, padded stride 33
    __shared__ float weLDS[4 * 128];   // 2KB: edge rows of W
    __shared__ float bLDS[128];
    int tid = threadIdx.x;
    int row0 = blockIdx.x * 64;
    for (int i = tid; i < 512; i += 256) weLDS[i] = W[128 * 128 + i];
    if (tid < 128) bLDS[tid] = bias[tid];

    int j0 = (tid & 31) * 4;
    int rbase = (tid >> 5) * 8;
    float acc[8][4];
#pragma unroll
    for (int m = 0; m < 8; ++m) { acc[m][0] = 0.f; acc[m][1] = 0.f; acc[m][2] = 0.f; acc[m][3] = 0.f; }

    for (int kc = 0; kc < 4; ++kc) {
        int k0 = kc * 32;
        // stage W chunk (contiguous 4096 floats)
        {
            const float4* wsrc = (const float4*)(W + k0 * 128);
            float4* wdst = (float4*)wLDS;
            for (int i = tid; i < 1024; i += 256) wdst[i] = wsrc[i];
        }
        // stage A chunk: 64 rows x 32 cols
        {
            int r = tid >> 2;            // 0..63
            int c = (tid & 3) * 8;       // 0,8,16,24
            int v = row0 + r;
            float4 p0 = make_float4(0.f, 0.f, 0.f, 0.f), p1 = p0;
            if (v < n) {
                const float4* src = (const float4*)(x + (size_t)v * 128 + k0 + c);
                p0 = src[0]; p1 = src[1];
            }
            float* d = &aLDS[r * 33 + c];
            d[0] = p0.x; d[1] = p0.y; d[2] = p0.z; d[3] = p0.w;
            d[4] = p1.x; d[5] = p1.y; d[6] = p1.z; d[7] = p1.w;
        }
        __syncthreads();
#pragma unroll 4
        for (int kk = 0; kk < 32; ++kk) {
            float4 wv = *(const float4*)&wLDS[kk * 128 + j0];
#pragma unroll
            for (int m = 0; m < 8; ++m) {
                float av = aLDS[(rbase + m) * 33 + kk];
                acc[m][0] += av * wv.x;
                acc[m][1] += av * wv.y;
                acc[m][2] += av * wv.z;
                acc[m][3] += av * wv.w;
            }
        }
        __syncthreads();
    }
    // epilogue
#pragma unroll
    for (int m = 0; m < 8; ++m) {
        int v = row0 + rbase + m;
        if (v < n) {
            float4 e = *(const float4*)(agg_e + (size_t)v * 4);
            float4 o;
            o.x = acc[m][0] + bLDS[j0 + 0] + e.x * weLDS[j0 + 0] + e.y * weLDS[128 + j0 + 0] + e.z * weLDS[256 + j0 + 0] + e.w * weLDS[384 + j0 + 0];
            o.y = acc[m][1] + bLDS[j0 + 1] + e.x * weLDS[j0 + 1] + e.y * weLDS[128 + j0 + 1] + e.z * weLDS[256 + j0 + 1] + e.w * weLDS[384 + j0 + 1];
            o.z = acc[m][2] + bLDS[j0 + 2] + e.x * weLDS[j0 + 2] + e.y * weLDS[128 + j0 + 2] + e.z * weLDS[256 + j0 + 2] + e.w * weLDS[384 + j0 + 2];
            o.w = acc[m][3] + bLDS[j0 + 3] + e.x * weLDS[j0 + 3] + e.y * weLDS[128 + j0 + 3] + e.z * weLDS[256 + j0 + 3] + e.w * weLDS[384 + j0 + 3];
            o.x = fmaxf(o.x, 0.f); o.y = fmaxf(o.y, 0.f); o.z = fmaxf(o.z, 0.f); o.w = fmaxf(o.w, 0.f);
            *(float4*)(x + (size_t)v * 128 + j0) = o;
        }
    }
}

// ---------------- pooling ----------------
__global__ __launch_bounds__(256) void k_pool(const float* __restrict__ x, const int* __restrict__ batch,
                                              float* __restrict__ pooled, int* __restrict__ gcnt, int n) {
    int wid = (blockIdx.x * 256 + threadIdx.x) >> 6;
    int lane = threadIdx.x & 63;
    if (wid >= n) return;
    int g = batch[wid];
    const float2* x2 = (const float2*)x;
    float2 v = x2[(size_t)wid * 64 + lane];
    atomicAdd(&pooled[g * 128 + lane * 2 + 0], v.x);
    atomicAdd(&pooled[g * 128 + lane * 2 + 1], v.y);
    if (lane == 0) atomicAdd(&gcnt[g], 1);
}

__global__ __launch_bounds__(128) void k_final(const float* __restrict__ pooled, const int* __restrict__ gcnt,
                                               const float* __restrict__ Wout, const float* __restrict__ bout,
                                               float* __restrict__ out, int G) {
    int g = threadIdx.x;
    if (g >= G) return;
    float c = (float)gcnt[g];
    if (c < 1.f) c = 1.f;
    float l0 = bout[0], l1 = bout[1], l2 = bout[2], l3 = bout[3];
    for (int k = 0; k < 128; ++k) {
        float p = pooled[g * 128 + k] / c;
        l0 += p * Wout[k * 4 + 0];
        l1 += p * Wout[k * 4 + 1];
        l2 += p * Wout[k * 4 + 2];
        l3 += p * Wout[k * 4 + 3];
    }
    float m = fmaxf(fmaxf(l0, l1), fmaxf(l2, l3));
    float s = expf(l0 - m) + expf(l1 - m) + expf(l2 - m) + expf(l3 - m);
    float ls = logf(s);
    out[g * 4 + 0] = l0 - m - ls;
    out[g * 4 + 1] = l1 - m - ls;
    out[g * 4 + 2] = l2 - m - ls;
    out[g * 4 + 3] = l3 - m - ls;
}

extern "C" void kernel_launch(void* const* d_in, const int* in_sizes, int n_in,
                              void* d_out, int out_size, void* d_ws, size_t ws_size,
                              hipStream_t stream) {
    const float* x    = (const float*)d_in[0];
    const int*   ei   = (const int*)d_in[1];
    const float* ea   = (const float*)d_in[2];
    const int*   bat  = (const int*)d_in[3];
    const float* W0   = (const float*)d_in[4];
    const float* b0   = (const float*)d_in[5];
    const float* W1   = (const float*)d_in[6];
    const float* b1   = (const float*)d_in[7];
    const float* W2   = (const float*)d_in[8];
    const float* b2   = (const float*)d_in[9];
    const float* Wout = (const float*)d_in[10];
    const float* bout = (const float*)d_in[11];
    float* out = (float*)d_out;

    int n = in_sizes[0] / 128;
    int E = in_sizes[1] / 2;
    int G = out_size / 4;

    char* w = (char*)d_ws;
    int* cnt       = (int*)w; w += (size_t)n * 4;
    int* fillpos   = (int*)w; w += (size_t)n * 4;
    int* row_ptr   = (int*)w; w += (size_t)n * 4;
    int* blockSums = (int*)w; w += 4096;
    int* blockOffs = (int*)w; w += 4096;
    int* csr_src   = (int*)w; w += (size_t)E * 4;
    float* agg_e   = (float*)w; w += (size_t)n * 16;
    float* pooled  = (float*)w; w += (size_t)G * 128 * 4;
    int* gcnt      = (int*)w; w += (size_t)((G + 3) / 4) * 16;
    float* bufA    = (float*)w; w += (size_t)n * 128 * 4;
    float* bufB    = (float*)w; w += (size_t)n * 128 * 4;

    hipMemsetAsync(cnt, 0, (size_t)n * 4, stream);
    hipMemsetAsync(fillpos, 0, (size_t)n * 4, stream);
    hipMemsetAsync(agg_e, 0, (size_t)n * 16, stream);
    hipMemsetAsync(pooled, 0, (size_t)G * 128 * 4, stream);
    hipMemsetAsync(gcnt, 0, (size_t)G * 4, stream);

    int eb = (E + 255) / 256;
    int nb = (n + 1023) / 1024;   // 98 for n=100000, fits k_scan2's 128 slots
    k_count<<<eb, 256, 0, stream>>>(ei, cnt, E);
    k_scan1<<<nb, 256, 0, stream>>>(cnt, row_ptr, blockSums, n);
    k_scan2<<<1, 128, 0, stream>>>(blockSums, blockOffs, nb);
    k_scan3<<<nb, 256, 0, stream>>>(row_ptr, blockOffs, n);
    k_fill<<<eb, 256, 0, stream>>>(ei, ea, row_ptr, fillpos, csr_src, agg_e, E);

    int gb = (n + 3) / 4;     // 4 waves/block, wave per node
    int mb = (n + 63) / 64;   // 64 rows per GEMM block

    k_gather<<<gb, 256, 0, stream>>>(x, bufA, row_ptr, cnt, csr_src, n);
    k_gemm<<<mb, 256, 0, stream>>>(bufA, agg_e, W0, b0, n);
    k_gather<<<gb, 256, 0, stream>>>(bufA, bufB, row_ptr, cnt, csr_src, n);
    k_gemm<<<mb, 256, 0, stream>>>(bufB, agg_e, W1, b1, n);
    k_gather<<<gb, 256, 0, stream>>>(bufB, bufA, row_ptr, cnt, csr_src, n);
    k_gemm<<<mb, 256, 0, stream>>>(bufA, agg_e, W2, b2, n);

    k_pool<<<gb, 256, 0, stream>>>(bufA, bat, pooled, gcnt, n);
    k_final<<<1, 128, 0, stream>>>(pooled, gcnt, Wout, bout, out, G);
}

// Round 2
// 1086.551 us; speedup vs baseline: 1.5069x; 1.5069x over previous
//
#include <hip/hip_runtime.h>

#define D_HID 128

// ---------------- CSR build ----------------

__global__ __launch_bounds__(256) void k_count(const int* __restrict__ ei, int* __restrict__ cnt, int E) {
    int e = blockIdx.x * 256 + threadIdx.x;
    if (e < E) atomicAdd(&cnt[ei[E + e]], 1);
}

__global__ __launch_bounds__(256) void k_scan1(const int* __restrict__ cnt, int* __restrict__ row_ptr,
                                               int* __restrict__ blockSums, int n) {
    __shared__ int sdata[256];
    int tid = threadIdx.x;
    int base = blockIdx.x * 1024 + tid * 4;
    int v0 = (base + 0 < n) ? cnt[base + 0] : 0;
    int v1 = (base + 1 < n) ? cnt[base + 1] : 0;
    int v2 = (base + 2 < n) ? cnt[base + 2] : 0;
    int v3 = (base + 3 < n) ? cnt[base + 3] : 0;
    int t = v0 + v1 + v2 + v3;
    int x = t;
    sdata[tid] = x; __syncthreads();
    for (int off = 1; off < 256; off <<= 1) {
        int y = (tid >= off) ? sdata[tid - off] : 0;
        __syncthreads();
        x += y;
        sdata[tid] = x;
        __syncthreads();
    }
    int p = x - t;  // exclusive prefix within block
    if (base + 0 < n) row_ptr[base + 0] = p;
    if (base + 1 < n) row_ptr[base + 1] = p + v0;
    if (base + 2 < n) row_ptr[base + 2] = p + v0 + v1;
    if (base + 3 < n) row_ptr[base + 3] = p + v0 + v1 + v2;
    if (tid == 255) blockSums[blockIdx.x] = x;
}

__global__ __launch_bounds__(128) void k_scan2(const int* __restrict__ blockSums, int* __restrict__ blockOffs, int nb) {
    __shared__ int sdata[128];
    int tid = threadIdx.x;
    int t = (tid < nb) ? blockSums[tid] : 0;
    int x = t;
    sdata[tid] = x; __syncthreads();
    for (int off = 1; off < 128; off <<= 1) {
        int y = (tid >= off) ? sdata[tid - off] : 0;
        __syncthreads();
        x += y;
        sdata[tid] = x;
        __syncthreads();
    }
    blockOffs[tid] = x - t;  // exclusive
}

__global__ __launch_bounds__(256) void k_scan3(int* __restrict__ row_ptr, const int* __restrict__ blockOffs, int n) {
    int add = blockOffs[blockIdx.x];
    int base = blockIdx.x * 1024 + threadIdx.x * 4;
    if (base + 0 < n) row_ptr[base + 0] += add;
    if (base + 1 < n) row_ptr[base + 1] += add;
    if (base + 2 < n) row_ptr[base + 2] += add;
    if (base + 3 < n) row_ptr[base + 3] += add;
}

__global__ __launch_bounds__(256) void k_fill(const int* __restrict__ ei, const float* __restrict__ ea,
                                              const int* __restrict__ row_ptr, int* __restrict__ fillpos,
                                              int* __restrict__ csr_src, float* __restrict__ agg_e, int E) {
    int e = blockIdx.x * 256 + threadIdx.x;
    if (e >= E) return;
    int s = ei[e];
    int d = ei[E + e];
    int p = atomicAdd(&fillpos[d], 1);
    csr_src[row_ptr[d] + p] = s;
    float4 a = ((const float4*)ea)[e];
    atomicAdd(&agg_e[d * 4 + 0], a.x);
    atomicAdd(&agg_e[d * 4 + 1], a.y);
    atomicAdd(&agg_e[d * 4 + 2], a.z);
    atomicAdd(&agg_e[d * 4 + 3], a.w);
}

// ---------------- per-layer: gather aggregation ----------------
// agg[v] = x[v] (self loop) + sum over incoming edges of x[src]
__global__ __launch_bounds__(256) void k_gather(const float* __restrict__ xin, float* __restrict__ agg,
                                                const int* __restrict__ row_ptr, const int* __restrict__ cnt,
                                                const int* __restrict__ csr_src, int n) {
    int wid = (blockIdx.x * 256 + threadIdx.x) >> 6;
    int lane = threadIdx.x & 63;
    if (wid >= n) return;
    const float2* x2 = (const float2*)xin;
    float2 acc = x2[(size_t)wid * 64 + lane];  // self loop
    int start = row_ptr[wid];
    int deg = cnt[wid];
    for (int base = 0; base < deg; base += 64) {
        int idx = 0;
        if (base + lane < deg) idx = csr_src[start + base + lane];
        int m = deg - base; if (m > 64) m = 64;
        for (int i = 0; i < m; ++i) {
            int s = __shfl(idx, i);
            float2 xv = x2[(size_t)s * 64 + lane];
            acc.x += xv.x; acc.y += xv.y;
        }
    }
    ((float2*)agg)[(size_t)wid * 64 + lane] = acc;
}

// ---------------- per-layer: GEMM + edge-bias + bias + relu, in-place ----------------
// x[v,:] = relu( agg_x[v,:] @ W[0:128,:] + agg_e[v,:] @ W[128:132,:] + b )
__global__ __launch_bounds__(256) void k_gemm(float* __restrict__ x, const float* __restrict__ agg_e,
                                              const float* __restrict__ W, const float* __restrict__ bias, int n) {
    __shared__ float wLDS[32 * 128];   // 16KB: W k-chunk
    __shared__ float aLDS[64 * 33];    // 8.4KB: A tile, padded stride 33
    __shared__ float weLDS[4 * 128];   // 2KB: edge rows of W
    __shared__ float bLDS[128];
    int tid = threadIdx.x;
    int row0 = blockIdx.x * 64;
    for (int i = tid; i < 512; i += 256) weLDS[i] = W[128 * 128 + i];
    if (tid < 128) bLDS[tid] = bias[tid];

    int j0 = (tid & 31) * 4;
    int rbase = (tid >> 5) * 8;
    float acc[8][4];
#pragma unroll
    for (int m = 0; m < 8; ++m) { acc[m][0] = 0.f; acc[m][1] = 0.f; acc[m][2] = 0.f; acc[m][3] = 0.f; }

    for (int kc = 0; kc < 4; ++kc) {
        int k0 = kc * 32;
        // stage W chunk (contiguous 4096 floats)
        {
            const float4* wsrc = (const float4*)(W + k0 * 128);
            float4* wdst = (float4*)wLDS;
            for (int i = tid; i < 1024; i += 256) wdst[i] = wsrc[i];
        }
        // stage A chunk: 64 rows x 32 cols
        {
            int r = tid >> 2;            // 0..63
            int c = (tid & 3) * 8;       // 0,8,16,24
            int v = row0 + r;
            float4 p0 = make_float4(0.f, 0.f, 0.f, 0.f), p1 = p0;
            if (v < n) {
                const float4* src = (const float4*)(x + (size_t)v * 128 + k0 + c);
                p0 = src[0]; p1 = src[1];
            }
            float* d = &aLDS[r * 33 + c];
            d[0] = p0.x; d[1] = p0.y; d[2] = p0.z; d[3] = p0.w;
            d[4] = p1.x; d[5] = p1.y; d[6] = p1.z; d[7] = p1.w;
        }
        __syncthreads();
#pragma unroll 4
        for (int kk = 0; kk < 32; ++kk) {
            float4 wv = *(const float4*)&wLDS[kk * 128 + j0];
#pragma unroll
            for (int m = 0; m < 8; ++m) {
                float av = aLDS[(rbase + m) * 33 + kk];
                acc[m][0] += av * wv.x;
                acc[m][1] += av * wv.y;
                acc[m][2] += av * wv.z;
                acc[m][3] += av * wv.w;
            }
        }
        __syncthreads();
    }
    // epilogue
#pragma unroll
    for (int m = 0; m < 8; ++m) {
        int v = row0 + rbase + m;
        if (v < n) {
            float4 e = *(const float4*)(agg_e + (size_t)v * 4);
            float4 o;
            o.x = acc[m][0] + bLDS[j0 + 0] + e.x * weLDS[j0 + 0] + e.y * weLDS[128 + j0 + 0] + e.z * weLDS[256 + j0 + 0] + e.w * weLDS[384 + j0 + 0];
            o.y = acc[m][1] + bLDS[j0 + 1] + e.x * weLDS[j0 + 1] + e.y * weLDS[128 + j0 + 1] + e.z * weLDS[256 + j0 + 1] + e.w * weLDS[384 + j0 + 1];
            o.z = acc[m][2] + bLDS[j0 + 2] + e.x * weLDS[j0 + 2] + e.y * weLDS[128 + j0 + 2] + e.z * weLDS[256 + j0 + 2] + e.w * weLDS[384 + j0 + 2];
            o.w = acc[m][3] + bLDS[j0 + 3] + e.x * weLDS[j0 + 3] + e.y * weLDS[128 + j0 + 3] + e.z * weLDS[256 + j0 + 3] + e.w * weLDS[384 + j0 + 3];
            o.x = fmaxf(o.x, 0.f); o.y = fmaxf(o.y, 0.f); o.z = fmaxf(o.z, 0.f); o.w = fmaxf(o.w, 0.f);
            *(float4*)(x + (size_t)v * 128 + j0) = o;
        }
    }
}

// ---------------- pooling (segmented: batch is sorted) ----------------

// gstart[g] = first node index of graph g; gstart[G] = n. Handles empty graphs.
__global__ __launch_bounds__(256) void k_bounds(const int* __restrict__ batch, int* __restrict__ gstart,
                                                int n, int G) {
    int i = blockIdx.x * 256 + threadIdx.x;
    if (i >= n) return;
    int g = batch[i];
    if (i == 0) {
        for (int q = 0; q <= g; ++q) gstart[q] = 0;
    } else {
        int gp = batch[i - 1];
        for (int q = gp + 1; q <= g; ++q) gstart[q] = i;
    }
    if (i == n - 1) {
        for (int q = g + 1; q <= G; ++q) gstart[q] = n;
    }
}

// One block per (graph, slice): register-accumulate 128 features over a
// contiguous node range, then ONE atomicAdd per feature per block.
#define POOL_S 16
__global__ __launch_bounds__(128) void k_pool2(const float* __restrict__ x, const int* __restrict__ gstart,
                                               float* __restrict__ pooled) {
    int g = blockIdx.x / POOL_S;
    int s = blockIdx.x % POOL_S;
    int t = threadIdx.x;
    int lo = gstart[g], hi = gstart[g + 1];
    int len = hi - lo;
    if (len <= 0) return;
    int chunk = (len + POOL_S - 1) / POOL_S;
    int a = lo + s * chunk;
    int b = a + chunk; if (b > hi) b = hi;
    if (a >= b) return;
    float acc = 0.f;
    for (int v = a; v < b; ++v) acc += x[(size_t)v * 128 + t];
    atomicAdd(&pooled[g * 128 + t], acc);
}

__global__ __launch_bounds__(128) void k_final(const float* __restrict__ pooled, const int* __restrict__ gstart,
                                               const float* __restrict__ Wout, const float* __restrict__ bout,
                                               float* __restrict__ out, int G) {
    int g = threadIdx.x;
    if (g >= G) return;
    float c = (float)(gstart[g + 1] - gstart[g]);
    if (c < 1.f) c = 1.f;
    float l0 = bout[0], l1 = bout[1], l2 = bout[2], l3 = bout[3];
    for (int k = 0; k < 128; ++k) {
        float p = pooled[g * 128 + k] / c;
        l0 += p * Wout[k * 4 + 0];
        l1 += p * Wout[k * 4 + 1];
        l2 += p * Wout[k * 4 + 2];
        l3 += p * Wout[k * 4 + 3];
    }
    float m = fmaxf(fmaxf(l0, l1), fmaxf(l2, l3));
    float s = expf(l0 - m) + expf(l1 - m) + expf(l2 - m) + expf(l3 - m);
    float ls = logf(s);
    out[g * 4 + 0] = l0 - m - ls;
    out[g * 4 + 1] = l1 - m - ls;
    out[g * 4 + 2] = l2 - m - ls;
    out[g * 4 + 3] = l3 - m - ls;
}

extern "C" void kernel_launch(void* const* d_in, const int* in_sizes, int n_in,
                              void* d_out, int out_size, void* d_ws, size_t ws_size,
                              hipStream_t stream) {
    const float* x    = (const float*)d_in[0];
    const int*   ei   = (const int*)d_in[1];
    const float* ea   = (const float*)d_in[2];
    const int*   bat  = (const int*)d_in[3];
    const float* W0   = (const float*)d_in[4];
    const float* b0   = (const float*)d_in[5];
    const float* W1   = (const float*)d_in[6];
    const float* b1   = (const float*)d_in[7];
    const float* W2   = (const float*)d_in[8];
    const float* b2   = (const float*)d_in[9];
    const float* Wout = (const float*)d_in[10];
    const float* bout = (const float*)d_in[11];
    float* out = (float*)d_out;

    int n = in_sizes[0] / 128;
    int E = in_sizes[1] / 2;
    int G = out_size / 4;

    char* w = (char*)d_ws;
    int* cnt       = (int*)w; w += (size_t)n * 4;
    int* fillpos   = (int*)w; w += (size_t)n * 4;
    int* row_ptr   = (int*)w; w += (size_t)n * 4;
    int* blockSums = (int*)w; w += 4096;
    int* blockOffs = (int*)w; w += 4096;
    int* csr_src   = (int*)w; w += (size_t)E * 4;
    float* agg_e   = (float*)w; w += (size_t)n * 16;
    float* pooled  = (float*)w; w += (size_t)G * 128 * 4;
    int* gstart    = (int*)w; w += (size_t)(G + 4) * 4;
    float* bufA    = (float*)w; w += (size_t)n * 128 * 4;
    float* bufB    = (float*)w; w += (size_t)n * 128 * 4;

    hipMemsetAsync(cnt, 0, (size_t)n * 4, stream);
    hipMemsetAsync(fillpos, 0, (size_t)n * 4, stream);
    hipMemsetAsync(agg_e, 0, (size_t)n * 16, stream);
    hipMemsetAsync(pooled, 0, (size_t)G * 128 * 4, stream);

    int eb = (E + 255) / 256;
    int nb = (n + 1023) / 1024;   // 98 for n=100000, fits k_scan2's 128 slots
    k_count<<<eb, 256, 0, stream>>>(ei, cnt, E);
    k_scan1<<<nb, 256, 0, stream>>>(cnt, row_ptr, blockSums, n);
    k_scan2<<<1, 128, 0, stream>>>(blockSums, blockOffs, nb);
    k_scan3<<<nb, 256, 0, stream>>>(row_ptr, blockOffs, n);
    k_fill<<<eb, 256, 0, stream>>>(ei, ea, row_ptr, fillpos, csr_src, agg_e, E);
    k_bounds<<<(n + 255) / 256, 256, 0, stream>>>(bat, gstart, n, G);

    int gb = (n + 3) / 4;     // 4 waves/block, wave per node
    int mb = (n + 63) / 64;   // 64 rows per GEMM block

    k_gather<<<gb, 256, 0, stream>>>(x, bufA, row_ptr, cnt, csr_src, n);
    k_gemm<<<mb, 256, 0, stream>>>(bufA, agg_e, W0, b0, n);
    k_gather<<<gb, 256, 0, stream>>>(bufA, bufB, row_ptr, cnt, csr_src, n);
    k_gemm<<<mb, 256, 0, stream>>>(bufB, agg_e, W1, b1, n);
    k_gather<<<gb, 256, 0, stream>>>(bufB, bufA, row_ptr, cnt, csr_src, n);
    k_gemm<<<mb, 256, 0, stream>>>(bufA, agg_e, W2, b2, n);

    k_pool2<<<G * POOL_S, 128, 0, stream>>>(bufA, gstart, pooled);
    k_final<<<1, 128, 0, stream>>>(pooled, gstart, Wout, bout, out, G);
}

// Round 3
// 866.372 us; speedup vs baseline: 1.8899x; 1.2541x over previous
//
#include <hip/hip_runtime.h>

#define D_HID 128

// ---------------- CSR build ----------------

__global__ __launch_bounds__(256) void k_count(const int* __restrict__ ei, int* __restrict__ cnt, int E) {
    int e = blockIdx.x * 256 + threadIdx.x;
    if (e < E) atomicAdd(&cnt[ei[E + e]], 1);
}

__global__ __launch_bounds__(256) void k_scan1(const int* __restrict__ cnt, int* __restrict__ row_ptr,
                                               int* __restrict__ blockSums, int n) {
    __shared__ int sdata[256];
    int tid = threadIdx.x;
    int base = blockIdx.x * 1024 + tid * 4;
    int v0 = (base + 0 < n) ? cnt[base + 0] : 0;
    int v1 = (base + 1 < n) ? cnt[base + 1] : 0;
    int v2 = (base + 2 < n) ? cnt[base + 2] : 0;
    int v3 = (base + 3 < n) ? cnt[base + 3] : 0;
    int t = v0 + v1 + v2 + v3;
    int x = t;
    sdata[tid] = x; __syncthreads();
    for (int off = 1; off < 256; off <<= 1) {
        int y = (tid >= off) ? sdata[tid - off] : 0;
        __syncthreads();
        x += y;
        sdata[tid] = x;
        __syncthreads();
    }
    int p = x - t;  // exclusive prefix within block
    if (base + 0 < n) row_ptr[base + 0] = p;
    if (base + 1 < n) row_ptr[base + 1] = p + v0;
    if (base + 2 < n) row_ptr[base + 2] = p + v0 + v1;
    if (base + 3 < n) row_ptr[base + 3] = p + v0 + v1 + v2;
    if (tid == 255) blockSums[blockIdx.x] = x;
}

__global__ __launch_bounds__(128) void k_scan2(const int* __restrict__ blockSums, int* __restrict__ blockOffs, int nb) {
    __shared__ int sdata[128];
    int tid = threadIdx.x;
    int t = (tid < nb) ? blockSums[tid] : 0;
    int x = t;
    sdata[tid] = x; __syncthreads();
    for (int off = 1; off < 128; off <<= 1) {
        int y = (tid >= off) ? sdata[tid - off] : 0;
        __syncthreads();
        x += y;
        sdata[tid] = x;
        __syncthreads();
    }
    blockOffs[tid] = x - t;  // exclusive
}

__global__ __launch_bounds__(256) void k_scan3(int* __restrict__ row_ptr, const int* __restrict__ blockOffs, int n) {
    int add = blockOffs[blockIdx.x];
    int base = blockIdx.x * 1024 + threadIdx.x * 4;
    if (base + 0 < n) row_ptr[base + 0] += add;
    if (base + 1 < n) row_ptr[base + 1] += add;
    if (base + 2 < n) row_ptr[base + 2] += add;
    if (base + 3 < n) row_ptr[base + 3] += add;
}

// One atomic + one 8B write per edge. row_head starts as a copy of row_ptr.
__global__ __launch_bounds__(256) void k_fill2(const int* __restrict__ ei, int* __restrict__ row_head,
                                               int2* __restrict__ csr2, int E) {
    int e = blockIdx.x * 256 + threadIdx.x;
    if (e >= E) return;
    int s = ei[e];
    int d = ei[E + e];
    int p = atomicAdd(&row_head[d], 1);
    csr2[p] = make_int2(s, e);
}

// agg_e[v] = sum of edge_attr over incoming edges. No atomics.
__global__ __launch_bounds__(256) void k_agge(const int2* __restrict__ csr2, const float* __restrict__ ea,
                                              const int* __restrict__ row_ptr, const int* __restrict__ cnt,
                                              float* __restrict__ agg_e, int n) {
    int v = blockIdx.x * 256 + threadIdx.x;
    if (v >= n) return;
    int start = row_ptr[v];
    int deg = cnt[v];
    float4 a = make_float4(0.f, 0.f, 0.f, 0.f);
    for (int i = 0; i < deg; ++i) {
        int eid = csr2[start + i].y;
        float4 t = ((const float4*)ea)[eid];
        a.x += t.x; a.y += t.y; a.z += t.z; a.w += t.w;
    }
    ((float4*)agg_e)[v] = a;
}

// ---------------- per-layer: gather aggregation ----------------
// agg[v] = x[v] (self loop) + sum over incoming edges of x[src]
__global__ __launch_bounds__(256) void k_gather(const float* __restrict__ xin, float* __restrict__ agg,
                                                const int* __restrict__ row_ptr, const int* __restrict__ cnt,
                                                const int2* __restrict__ csr2, int n) {
    int wid = (blockIdx.x * 256 + threadIdx.x) >> 6;
    int lane = threadIdx.x & 63;
    if (wid >= n) return;
    const float2* x2 = (const float2*)xin;
    float2 acc = x2[(size_t)wid * 64 + lane];  // self loop
    int start = row_ptr[wid];
    int deg = cnt[wid];
    for (int base = 0; base < deg; base += 64) {
        int idx = 0;
        if (base + lane < deg) idx = csr2[start + base + lane].x;
        int m = deg - base; if (m > 64) m = 64;
        for (int i = 0; i < m; ++i) {
            int s = __shfl(idx, i);
            float2 xv = x2[(size_t)s * 64 + lane];
            acc.x += xv.x; acc.y += xv.y;
        }
    }
    ((float2*)agg)[(size_t)wid * 64 + lane] = acc;
}

// ---------------- per-layer: GEMM + edge-bias + bias + relu, in-place ----------------
// x[v,:] = relu( agg_x[v,:] @ W[0:128,:] + agg_e[v,:] @ W[128:132,:] + b )
__global__ __launch_bounds__(256) void k_gemm(float* __restrict__ x, const float* __restrict__ agg_e,
                                              const float* __restrict__ W, const float* __restrict__ bias, int n) {
    __shared__ float wLDS[32 * 128];   // 16KB: W k-chunk
    __shared__ float aLDS[64 * 33];    // 8.4KB: A tile, padded stride 33
    __shared__ float weLDS[4 * 128];   // 2KB: edge rows of W
    __shared__ float bLDS[128];
    int tid = threadIdx.x;
    int row0 = blockIdx.x * 64;
    for (int i = tid; i < 512; i += 256) weLDS[i] = W[128 * 128 + i];
    if (tid < 128) bLDS[tid] = bias[tid];

    int j0 = (tid & 31) * 4;
    int rbase = (tid >> 5) * 8;
    float acc[8][4];
#pragma unroll
    for (int m = 0; m < 8; ++m) { acc[m][0] = 0.f; acc[m][1] = 0.f; acc[m][2] = 0.f; acc[m][3] = 0.f; }

    for (int kc = 0; kc < 4; ++kc) {
        int k0 = kc * 32;
        // stage W chunk (contiguous 4096 floats)
        {
            const float4* wsrc = (const float4*)(W + k0 * 128);
            float4* wdst = (float4*)wLDS;
            for (int i = tid; i < 1024; i += 256) wdst[i] = wsrc[i];
        }
        // stage A chunk: 64 rows x 32 cols
        {
            int r = tid >> 2;            // 0..63
            int c = (tid & 3) * 8;       // 0,8,16,24
            int v = row0 + r;
            float4 p0 = make_float4(0.f, 0.f, 0.f, 0.f), p1 = p0;
            if (v < n) {
                const float4* src = (const float4*)(x + (size_t)v * 128 + k0 + c);
                p0 = src[0]; p1 = src[1];
            }
            float* d = &aLDS[r * 33 + c];
            d[0] = p0.x; d[1] = p0.y; d[2] = p0.z; d[3] = p0.w;
            d[4] = p1.x; d[5] = p1.y; d[6] = p1.z; d[7] = p1.w;
        }
        __syncthreads();
#pragma unroll 4
        for (int kk = 0; kk < 32; ++kk) {
            float4 wv = *(const float4*)&wLDS[kk * 128 + j0];
#pragma unroll
            for (int m = 0; m < 8; ++m) {
                float av = aLDS[(rbase + m) * 33 + kk];
                acc[m][0] += av * wv.x;
                acc[m][1] += av * wv.y;
                acc[m][2] += av * wv.z;
                acc[m][3] += av * wv.w;
            }
        }
        __syncthreads();
    }
    // epilogue
#pragma unroll
    for (int m = 0; m < 8; ++m) {
        int v = row0 + rbase + m;
        if (v < n) {
            float4 e = *(const float4*)(agg_e + (size_t)v * 4);
            float4 o;
            o.x = acc[m][0] + bLDS[j0 + 0] + e.x * weLDS[j0 + 0] + e.y * weLDS[128 + j0 + 0] + e.z * weLDS[256 + j0 + 0] + e.w * weLDS[384 + j0 + 0];
            o.y = acc[m][1] + bLDS[j0 + 1] + e.x * weLDS[j0 + 1] + e.y * weLDS[128 + j0 + 1] + e.z * weLDS[256 + j0 + 1] + e.w * weLDS[384 + j0 + 1];
            o.z = acc[m][2] + bLDS[j0 + 2] + e.x * weLDS[j0 + 2] + e.y * weLDS[128 + j0 + 2] + e.z * weLDS[256 + j0 + 2] + e.w * weLDS[384 + j0 + 2];
            o.w = acc[m][3] + bLDS[j0 + 3] + e.x * weLDS[j0 + 3] + e.y * weLDS[128 + j0 + 3] + e.z * weLDS[256 + j0 + 3] + e.w * weLDS[384 + j0 + 3];
            o.x = fmaxf(o.x, 0.f); o.y = fmaxf(o.y, 0.f); o.z = fmaxf(o.z, 0.f); o.w = fmaxf(o.w, 0.f);
            *(float4*)(x + (size_t)v * 128 + j0) = o;
        }
    }
}

// ---------------- pooling (segmented: batch is sorted) ----------------

__global__ __launch_bounds__(256) void k_bounds(const int* __restrict__ batch, int* __restrict__ gstart,
                                                int n, int G) {
    int i = blockIdx.x * 256 + threadIdx.x;
    if (i >= n) return;
    int g = batch[i];
    if (i == 0) {
        for (int q = 0; q <= g; ++q) gstart[q] = 0;
    } else {
        int gp = batch[i - 1];
        for (int q = gp + 1; q <= g; ++q) gstart[q] = i;
    }
    if (i == n - 1) {
        for (int q = g + 1; q <= G; ++q) gstart[q] = n;
    }
}

#define POOL_S 16
__global__ __launch_bounds__(128) void k_pool2(const float* __restrict__ x, const int* __restrict__ gstart,
                                               float* __restrict__ pooled) {
    int g = blockIdx.x / POOL_S;
    int s = blockIdx.x % POOL_S;
    int t = threadIdx.x;
    int lo = gstart[g], hi = gstart[g + 1];
    int len = hi - lo;
    if (len <= 0) return;
    int chunk = (len + POOL_S - 1) / POOL_S;
    int a = lo + s * chunk;
    int b = a + chunk; if (b > hi) b = hi;
    if (a >= b) return;
    float acc = 0.f;
    for (int v = a; v < b; ++v) acc += x[(size_t)v * 128 + t];
    atomicAdd(&pooled[g * 128 + t], acc);
}

__global__ __launch_bounds__(128) void k_final(const float* __restrict__ pooled, const int* __restrict__ gstart,
                                               const float* __restrict__ Wout, const float* __restrict__ bout,
                                               float* __restrict__ out, int G) {
    int g = threadIdx.x;
    if (g >= G) return;
    float c = (float)(gstart[g + 1] - gstart[g]);
    if (c < 1.f) c = 1.f;
    float l0 = bout[0], l1 = bout[1], l2 = bout[2], l3 = bout[3];
    for (int k = 0; k < 128; ++k) {
        float p = pooled[g * 128 + k] / c;
        l0 += p * Wout[k * 4 + 0];
        l1 += p * Wout[k * 4 + 1];
        l2 += p * Wout[k * 4 + 2];
        l3 += p * Wout[k * 4 + 3];
    }
    float m = fmaxf(fmaxf(l0, l1), fmaxf(l2, l3));
    float s = expf(l0 - m) + expf(l1 - m) + expf(l2 - m) + expf(l3 - m);
    float ls = logf(s);
    out[g * 4 + 0] = l0 - m - ls;
    out[g * 4 + 1] = l1 - m - ls;
    out[g * 4 + 2] = l2 - m - ls;
    out[g * 4 + 3] = l3 - m - ls;
}

extern "C" void kernel_launch(void* const* d_in, const int* in_sizes, int n_in,
                              void* d_out, int out_size, void* d_ws, size_t ws_size,
                              hipStream_t stream) {
    const float* x    = (const float*)d_in[0];
    const int*   ei   = (const int*)d_in[1];
    const float* ea   = (const float*)d_in[2];
    const int*   bat  = (const int*)d_in[3];
    const float* W0   = (const float*)d_in[4];
    const float* b0   = (const float*)d_in[5];
    const float* W1   = (const float*)d_in[6];
    const float* b1   = (const float*)d_in[7];
    const float* W2   = (const float*)d_in[8];
    const float* b2   = (const float*)d_in[9];
    const float* Wout = (const float*)d_in[10];
    const float* bout = (const float*)d_in[11];
    float* out = (float*)d_out;

    int n = in_sizes[0] / 128;
    int E = in_sizes[1] / 2;
    int G = out_size / 4;

    char* w = (char*)d_ws;
    int* cnt       = (int*)w; w += (size_t)n * 4;
    int* row_head  = (int*)w; w += (size_t)n * 4;
    int* row_ptr   = (int*)w; w += (size_t)n * 4;
    int* blockSums = (int*)w; w += 4096;
    int* blockOffs = (int*)w; w += 4096;
    int2* csr2     = (int2*)w; w += (size_t)E * 8;
    float* agg_e   = (float*)w; w += (size_t)n * 16;
    float* pooled  = (float*)w; w += (size_t)G * 128 * 4;
    int* gstart    = (int*)w; w += (size_t)(G + 4) * 4;
    float* bufA    = (float*)w; w += (size_t)n * 128 * 4;
    float* bufB    = (float*)w; w += (size_t)n * 128 * 4;

    hipMemsetAsync(cnt, 0, (size_t)n * 4, stream);
    hipMemsetAsync(pooled, 0, (size_t)G * 128 * 4, stream);

    int eb = (E + 255) / 256;
    int nb = (n + 1023) / 1024;   // 98 for n=100000, fits k_scan2's 128 slots
    k_count<<<eb, 256, 0, stream>>>(ei, cnt, E);
    k_scan1<<<nb, 256, 0, stream>>>(cnt, row_ptr, blockSums, n);
    k_scan2<<<1, 128, 0, stream>>>(blockSums, blockOffs, nb);
    k_scan3<<<nb, 256, 0, stream>>>(row_ptr, blockOffs, n);
    hipMemcpyAsync(row_head, row_ptr, (size_t)n * 4, hipMemcpyDeviceToDevice, stream);
    k_fill2<<<eb, 256, 0, stream>>>(ei, row_head, csr2, E);
    k_agge<<<(n + 255) / 256, 256, 0, stream>>>(csr2, ea, row_ptr, cnt, agg_e, n);
    k_bounds<<<(n + 255) / 256, 256, 0, stream>>>(bat, gstart, n, G);

    int gb = (n + 3) / 4;     // 4 waves/block, wave per node
    int mb = (n + 63) / 64;   // 64 rows per GEMM block

    k_gather<<<gb, 256, 0, stream>>>(x, bufA, row_ptr, cnt, csr2, n);
    k_gemm<<<mb, 256, 0, stream>>>(bufA, agg_e, W0, b0, n);
    k_gather<<<gb, 256, 0, stream>>>(bufA, bufB, row_ptr, cnt, csr2, n);
    k_gemm<<<mb, 256, 0, stream>>>(bufB, agg_e, W1, b1, n);
    k_gather<<<gb, 256, 0, stream>>>(bufB, bufA, row_ptr, cnt, csr2, n);
    k_gemm<<<mb, 256, 0, stream>>>(bufA, agg_e, W2, b2, n);

    k_pool2<<<G * POOL_S, 128, 0, stream>>>(bufA, gstart, pooled);
    k_final<<<1, 128, 0, stream>>>(pooled, gstart, Wout, bout, out, G);
}

// Round 4
// 778.106 us; speedup vs baseline: 2.1043x; 1.1134x over previous
//
#include <hip/hip_runtime.h>

// ---------------- bf16 helpers ----------------
__device__ inline ushort f2bf(float f) {
    unsigned u = __float_as_uint(f);
    u += 0x7fffu + ((u >> 16) & 1u);   // round-to-nearest-even
    return (ushort)(u >> 16);
}
__device__ inline float bf2f(ushort h) { return __uint_as_float(((unsigned)h) << 16); }

// ---------------- CSR build ----------------

__global__ __launch_bounds__(256) void k_count(const int* __restrict__ ei, int* __restrict__ cnt, int E) {
    int e = blockIdx.x * 256 + threadIdx.x;
    if (e < E) atomicAdd(&cnt[ei[E + e]], 1);
}

__global__ __launch_bounds__(256) void k_scan1(const int* __restrict__ cnt, int* __restrict__ row_ptr,
                                               int* __restrict__ blockSums, int n) {
    __shared__ int sdata[256];
    int tid = threadIdx.x;
    int base = blockIdx.x * 1024 + tid * 4;
    int v0 = (base + 0 < n) ? cnt[base + 0] : 0;
    int v1 = (base + 1 < n) ? cnt[base + 1] : 0;
    int v2 = (base + 2 < n) ? cnt[base + 2] : 0;
    int v3 = (base + 3 < n) ? cnt[base + 3] : 0;
    int t = v0 + v1 + v2 + v3;
    int x = t;
    sdata[tid] = x; __syncthreads();
    for (int off = 1; off < 256; off <<= 1) {
        int y = (tid >= off) ? sdata[tid - off] : 0;
        __syncthreads();
        x += y;
        sdata[tid] = x;
        __syncthreads();
    }
    int p = x - t;  // exclusive prefix within block
    if (base + 0 < n) row_ptr[base + 0] = p;
    if (base + 1 < n) row_ptr[base + 1] = p + v0;
    if (base + 2 < n) row_ptr[base + 2] = p + v0 + v1;
    if (base + 3 < n) row_ptr[base + 3] = p + v0 + v1 + v2;
    if (tid == 255) blockSums[blockIdx.x] = x;
}

__global__ __launch_bounds__(128) void k_scan2(const int* __restrict__ blockSums, int* __restrict__ blockOffs, int nb) {
    __shared__ int sdata[128];
    int tid = threadIdx.x;
    int t = (tid < nb) ? blockSums[tid] : 0;
    int x = t;
    sdata[tid] = x; __syncthreads();
    for (int off = 1; off < 128; off <<= 1) {
        int y = (tid >= off) ? sdata[tid - off] : 0;
        __syncthreads();
        x += y;
        sdata[tid] = x;
        __syncthreads();
    }
    blockOffs[tid] = x - t;  // exclusive
}

__global__ __launch_bounds__(256) void k_scan3(int* __restrict__ row_ptr, const int* __restrict__ blockOffs, int n) {
    int add = blockOffs[blockIdx.x];
    int base = blockIdx.x * 1024 + threadIdx.x * 4;
    if (base + 0 < n) row_ptr[base + 0] += add;
    if (base + 1 < n) row_ptr[base + 1] += add;
    if (base + 2 < n) row_ptr[base + 2] += add;
    if (base + 3 < n) row_ptr[base + 3] += add;
}

// One atomic + one 8B write per edge. row_head starts as a copy of row_ptr.
__global__ __launch_bounds__(256) void k_fill2(const int* __restrict__ ei, int* __restrict__ row_head,
                                               int2* __restrict__ csr2, int E) {
    int e = blockIdx.x * 256 + threadIdx.x;
    if (e >= E) return;
    int s = ei[e];
    int d = ei[E + e];
    int p = atomicAdd(&row_head[d], 1);
    csr2[p] = make_int2(s, e);
}

// agg_e[v] = sum of edge_attr over incoming edges. No atomics.
__global__ __launch_bounds__(256) void k_agge(const int2* __restrict__ csr2, const float* __restrict__ ea,
                                              const int* __restrict__ row_ptr, const int* __restrict__ cnt,
                                              float* __restrict__ agg_e, int n) {
    int v = blockIdx.x * 256 + threadIdx.x;
    if (v >= n) return;
    int start = row_ptr[v];
    int deg = cnt[v];
    float4 a = make_float4(0.f, 0.f, 0.f, 0.f);
    for (int i = 0; i < deg; ++i) {
        int eid = csr2[start + i].y;
        float4 t = ((const float4*)ea)[eid];
        a.x += t.x; a.y += t.y; a.z += t.z; a.w += t.w;
    }
    ((float4*)agg_e)[v] = a;
}

// ---------------- fp32 -> bf16 convert (one-time) ----------------
__global__ __launch_bounds__(256) void k_cvt(const float* __restrict__ in, ushort* __restrict__ out, int total4) {
    int i = blockIdx.x * 256 + threadIdx.x;
    if (i >= total4) return;
    float4 v = ((const float4*)in)[i];
    unsigned lo = (unsigned)f2bf(v.x) | ((unsigned)f2bf(v.y) << 16);
    unsigned hi = (unsigned)f2bf(v.z) | ((unsigned)f2bf(v.w) << 16);
    ((uint2*)out)[i] = make_uint2(lo, hi);
}

// ---------------- per-layer: gather aggregation (bf16 rows, fp32 accum) ----------------
__global__ __launch_bounds__(256) void k_gather_b(const ushort* __restrict__ xb, ushort* __restrict__ aggb,
                                                  const int* __restrict__ row_ptr, const int* __restrict__ cnt,
                                                  const int2* __restrict__ csr2, int n) {
    int wid = (blockIdx.x * 256 + threadIdx.x) >> 6;
    int lane = threadIdx.x & 63;
    if (wid >= n) return;
    const unsigned* x2 = (const unsigned*)xb;  // 2 bf16 per uint
    unsigned self = x2[(size_t)wid * 64 + lane];
    float ax = bf2f((ushort)(self & 0xffffu));
    float ay = bf2f((ushort)(self >> 16));
    int start = row_ptr[wid];
    int deg = cnt[wid];
    for (int base = 0; base < deg; base += 64) {
        int idx = 0;
        if (base + lane < deg) idx = csr2[start + base + lane].x;
        int m = deg - base; if (m > 64) m = 64;
        for (int i = 0; i < m; ++i) {
            int s = __shfl(idx, i);
            unsigned xv = x2[(size_t)s * 64 + lane];
            ax += bf2f((ushort)(xv & 0xffffu));
            ay += bf2f((ushort)(xv >> 16));
        }
    }
    ((unsigned*)aggb)[(size_t)wid * 64 + lane] = (unsigned)f2bf(ax) | ((unsigned)f2bf(ay) << 16);
}

// ---------------- per-layer: GEMM + edge-bias + bias + relu ----------------
// xb_out[v,:] = bf16( relu( agg[v,:] @ W[0:128,:] + agg_e[v,:] @ W[128:132,:] + b ) )
__global__ __launch_bounds__(256) void k_gemm_b(const ushort* __restrict__ aggb, ushort* __restrict__ xb_out,
                                                const float* __restrict__ agg_e,
                                                const float* __restrict__ W, const float* __restrict__ bias, int n) {
    __shared__ float wLDS[32 * 128];   // 16KB: W k-chunk
    __shared__ float aLDS[64 * 33];    // 8.4KB: A tile (fp32), padded stride 33
    __shared__ float weLDS[4 * 128];   // 2KB: edge rows of W
    __shared__ float bLDS[128];
    int tid = threadIdx.x;
    int row0 = blockIdx.x * 64;
    for (int i = tid; i < 512; i += 256) weLDS[i] = W[128 * 128 + i];
    if (tid < 128) bLDS[tid] = bias[tid];

    int j0 = (tid & 31) * 4;
    int rbase = (tid >> 5) * 8;
    float acc[8][4];
#pragma unroll
    for (int m = 0; m < 8; ++m) { acc[m][0] = 0.f; acc[m][1] = 0.f; acc[m][2] = 0.f; acc[m][3] = 0.f; }

    for (int kc = 0; kc < 4; ++kc) {
        int k0 = kc * 32;
        // stage W chunk (contiguous 4096 floats)
        {
            const float4* wsrc = (const float4*)(W + k0 * 128);
            float4* wdst = (float4*)wLDS;
            for (int i = tid; i < 1024; i += 256) wdst[i] = wsrc[i];
        }
        // stage A chunk: 64 rows x 32 cols, bf16 -> fp32
        {
            int r = tid >> 2;            // 0..63
            int c = (tid & 3) * 8;       // 0,8,16,24
            int v = row0 + r;
            uint4 p = make_uint4(0u, 0u, 0u, 0u);
            if (v < n) p = *(const uint4*)(aggb + (size_t)v * 128 + k0 + c);  // 8 bf16
            float* d = &aLDS[r * 33 + c];
            d[0] = bf2f((ushort)(p.x & 0xffffu)); d[1] = bf2f((ushort)(p.x >> 16));
            d[2] = bf2f((ushort)(p.y & 0xffffu)); d[3] = bf2f((ushort)(p.y >> 16));
            d[4] = bf2f((ushort)(p.z & 0xffffu)); d[5] = bf2f((ushort)(p.z >> 16));
            d[6] = bf2f((ushort)(p.w & 0xffffu)); d[7] = bf2f((ushort)(p.w >> 16));
        }
        __syncthreads();
#pragma unroll 4
        for (int kk = 0; kk < 32; ++kk) {
            float4 wv = *(const float4*)&wLDS[kk * 128 + j0];
#pragma unroll
            for (int m = 0; m < 8; ++m) {
                float av = aLDS[(rbase + m) * 33 + kk];
                acc[m][0] += av * wv.x;
                acc[m][1] += av * wv.y;
                acc[m][2] += av * wv.z;
                acc[m][3] += av * wv.w;
            }
        }
        __syncthreads();
    }
    // epilogue
#pragma unroll
    for (int m = 0; m < 8; ++m) {
        int v = row0 + rbase + m;
        if (v < n) {
            float4 e = *(const float4*)(agg_e + (size_t)v * 4);
            float4 o;
            o.x = acc[m][0] + bLDS[j0 + 0] + e.x * weLDS[j0 + 0] + e.y * weLDS[128 + j0 + 0] + e.z * weLDS[256 + j0 + 0] + e.w * weLDS[384 + j0 + 0];
            o.y = acc[m][1] + bLDS[j0 + 1] + e.x * weLDS[j0 + 1] + e.y * weLDS[128 + j0 + 1] + e.z * weLDS[256 + j0 + 1] + e.w * weLDS[384 + j0 + 1];
            o.z = acc[m][2] + bLDS[j0 + 2] + e.x * weLDS[j0 + 2] + e.y * weLDS[128 + j0 + 2] + e.z * weLDS[256 + j0 + 2] + e.w * weLDS[384 + j0 + 2];
            o.w = acc[m][3] + bLDS[j0 + 3] + e.x * weLDS[j0 + 3] + e.y * weLDS[128 + j0 + 3] + e.z * weLDS[256 + j0 + 3] + e.w * weLDS[384 + j0 + 3];
            o.x = fmaxf(o.x, 0.f); o.y = fmaxf(o.y, 0.f); o.z = fmaxf(o.z, 0.f); o.w = fmaxf(o.w, 0.f);
            unsigned lo = (unsigned)f2bf(o.x) | ((unsigned)f2bf(o.y) << 16);
            unsigned hi = (unsigned)f2bf(o.z) | ((unsigned)f2bf(o.w) << 16);
            *(uint2*)(xb_out + (size_t)v * 128 + j0) = make_uint2(lo, hi);
        }
    }
}

// ---------------- pooling (segmented: batch is sorted) ----------------

__global__ __launch_bounds__(256) void k_bounds(const int* __restrict__ batch, int* __restrict__ gstart,
                                                int n, int G) {
    int i = blockIdx.x * 256 + threadIdx.x;
    if (i >= n) return;
    int g = batch[i];
    if (i == 0) {
        for (int q = 0; q <= g; ++q) gstart[q] = 0;
    } else {
        int gp = batch[i - 1];
        for (int q = gp + 1; q <= g; ++q) gstart[q] = i;
    }
    if (i == n - 1) {
        for (int q = g + 1; q <= G; ++q) gstart[q] = n;
    }
}

#define POOL_S 16
__global__ __launch_bounds__(128) void k_pool2(const ushort* __restrict__ xb, const int* __restrict__ gstart,
                                               float* __restrict__ pooled) {
    int g = blockIdx.x / POOL_S;
    int s = blockIdx.x % POOL_S;
    int t = threadIdx.x;
    int lo = gstart[g], hi = gstart[g + 1];
    int len = hi - lo;
    if (len <= 0) return;
    int chunk = (len + POOL_S - 1) / POOL_S;
    int a = lo + s * chunk;
    int b = a + chunk; if (b > hi) b = hi;
    if (a >= b) return;
    float acc = 0.f;
    for (int v = a; v < b; ++v) acc += bf2f(xb[(size_t)v * 128 + t]);
    atomicAdd(&pooled[g * 128 + t], acc);
}

__global__ __launch_bounds__(128) void k_final(const float* __restrict__ pooled, const int* __restrict__ gstart,
                                               const float* __restrict__ Wout, const float* __restrict__ bout,
                                               float* __restrict__ out, int G) {
    int g = threadIdx.x;
    if (g >= G) return;
    float c = (float)(gstart[g + 1] - gstart[g]);
    if (c < 1.f) c = 1.f;
    float l0 = bout[0], l1 = bout[1], l2 = bout[2], l3 = bout[3];
    for (int k = 0; k < 128; ++k) {
        float p = pooled[g * 128 + k] / c;
        l0 += p * Wout[k * 4 + 0];
        l1 += p * Wout[k * 4 + 1];
        l2 += p * Wout[k * 4 + 2];
        l3 += p * Wout[k * 4 + 3];
    }
    float m = fmaxf(fmaxf(l0, l1), fmaxf(l2, l3));
    float s = expf(l0 - m) + expf(l1 - m) + expf(l2 - m) + expf(l3 - m);
    float ls = logf(s);
    out[g * 4 + 0] = l0 - m - ls;
    out[g * 4 + 1] = l1 - m - ls;
    out[g * 4 + 2] = l2 - m - ls;
    out[g * 4 + 3] = l3 - m - ls;
}

extern "C" void kernel_launch(void* const* d_in, const int* in_sizes, int n_in,
                              void* d_out, int out_size, void* d_ws, size_t ws_size,
                              hipStream_t stream) {
    const float* x    = (const float*)d_in[0];
    const int*   ei   = (const int*)d_in[1];
    const float* ea   = (const float*)d_in[2];
    const int*   bat  = (const int*)d_in[3];
    const float* W0   = (const float*)d_in[4];
    const float* b0   = (const float*)d_in[5];
    const float* W1   = (const float*)d_in[6];
    const float* b1   = (const float*)d_in[7];
    const float* W2   = (const float*)d_in[8];
    const float* b2   = (const float*)d_in[9];
    const float* Wout = (const float*)d_in[10];
    const float* bout = (const float*)d_in[11];
    float* out = (float*)d_out;

    int n = in_sizes[0] / 128;
    int E = in_sizes[1] / 2;
    int G = out_size / 4;

    char* w = (char*)d_ws;
    int* cnt       = (int*)w; w += (size_t)n * 4;
    int* row_head  = (int*)w; w += (size_t)n * 4;
    int* row_ptr   = (int*)w; w += (size_t)n * 4;
    int* blockSums = (int*)w; w += 4096;
    int* blockOffs = (int*)w; w += 4096;
    int2* csr2     = (int2*)w; w += (size_t)E * 8;
    float* agg_e   = (float*)w; w += (size_t)n * 16;
    float* pooled  = (float*)w; w += (size_t)G * 128 * 4;
    int* gstart    = (int*)w; w += (size_t)(G + 4) * 4;
    ushort* xb     = (ushort*)w; w += (size_t)n * 128 * 2;
    ushort* aggb   = (ushort*)w; w += (size_t)n * 128 * 2;

    hipMemsetAsync(cnt, 0, (size_t)n * 4, stream);
    hipMemsetAsync(pooled, 0, (size_t)G * 128 * 4, stream);

    int eb = (E + 255) / 256;
    int nb = (n + 1023) / 1024;   // 98 for n=100000, fits k_scan2's 128 slots
    k_count<<<eb, 256, 0, stream>>>(ei, cnt, E);
    k_scan1<<<nb, 256, 0, stream>>>(cnt, row_ptr, blockSums, n);
    k_scan2<<<1, 128, 0, stream>>>(blockSums, blockOffs, nb);
    k_scan3<<<nb, 256, 0, stream>>>(row_ptr, blockOffs, n);
    hipMemcpyAsync(row_head, row_ptr, (size_t)n * 4, hipMemcpyDeviceToDevice, stream);
    k_fill2<<<eb, 256, 0, stream>>>(ei, row_head, csr2, E);
    k_agge<<<(n + 255) / 256, 256, 0, stream>>>(csr2, ea, row_ptr, cnt, agg_e, n);
    k_bounds<<<(n + 255) / 256, 256, 0, stream>>>(bat, gstart, n, G);
    k_cvt<<<(n * 32 + 255) / 256, 256, 0, stream>>>(x, xb, n * 32);  // n*128/4 items

    int gb = (n + 3) / 4;     // 4 waves/block, wave per node
    int mb = (n + 63) / 64;   // 64 rows per GEMM block

    k_gather_b<<<gb, 256, 0, stream>>>(xb, aggb, row_ptr, cnt, csr2, n);
    k_gemm_b<<<mb, 256, 0, stream>>>(aggb, xb, agg_e, W0, b0, n);
    k_gather_b<<<gb, 256, 0, stream>>>(xb, aggb, row_ptr, cnt, csr2, n);
    k_gemm_b<<<mb, 256, 0, stream>>>(aggb, xb, agg_e, W1, b1, n);
    k_gather_b<<<gb, 256, 0, stream>>>(xb, aggb, row_ptr, cnt, csr2, n);
    k_gemm_b<<<mb, 256, 0, stream>>>(aggb, xb, agg_e, W2, b2, n);

    k_pool2<<<G * POOL_S, 128, 0, stream>>>(xb, gstart, pooled);
    k_final<<<1, 128, 0, stream>>>(pooled, gstart, Wout, bout, out, G);
}

// Round 5
// 736.393 us; speedup vs baseline: 2.2235x; 1.0566x over previous
//
#include <hip/hip_runtime.h>

typedef __attribute__((ext_vector_type(8))) short short8;
typedef __attribute__((ext_vector_type(4))) float f32x4;

// ---------------- bf16 helpers ----------------
__device__ inline ushort f2bf(float f) {
    unsigned u = __float_as_uint(f);
    u += 0x7fffu + ((u >> 16) & 1u);   // round-to-nearest-even
    return (ushort)(u >> 16);
}
__device__ inline float bf2f(ushort h) { return __uint_as_float(((unsigned)h) << 16); }

// ---------------- CSR build ----------------

__global__ __launch_bounds__(256) void k_count(const int* __restrict__ ei, int* __restrict__ cnt, int E) {
    int e = blockIdx.x * 256 + threadIdx.x;
    if (e < E) atomicAdd(&cnt[ei[E + e]], 1);
}

__global__ __launch_bounds__(256) void k_scan1(const int* __restrict__ cnt, int* __restrict__ row_ptr,
                                               int* __restrict__ blockSums, int n) {
    __shared__ int sdata[256];
    int tid = threadIdx.x;
    int base = blockIdx.x * 1024 + tid * 4;
    int v0 = (base + 0 < n) ? cnt[base + 0] : 0;
    int v1 = (base + 1 < n) ? cnt[base + 1] : 0;
    int v2 = (base + 2 < n) ? cnt[base + 2] : 0;
    int v3 = (base + 3 < n) ? cnt[base + 3] : 0;
    int t = v0 + v1 + v2 + v3;
    int x = t;
    sdata[tid] = x; __syncthreads();
    for (int off = 1; off < 256; off <<= 1) {
        int y = (tid >= off) ? sdata[tid - off] : 0;
        __syncthreads();
        x += y;
        sdata[tid] = x;
        __syncthreads();
    }
    int p = x - t;  // exclusive prefix within block
    if (base + 0 < n) row_ptr[base + 0] = p;
    if (base + 1 < n) row_ptr[base + 1] = p + v0;
    if (base + 2 < n) row_ptr[base + 2] = p + v0 + v1;
    if (base + 3 < n) row_ptr[base + 3] = p + v0 + v1 + v2;
    if (tid == 255) blockSums[blockIdx.x] = x;
}

__global__ __launch_bounds__(128) void k_scan2(const int* __restrict__ blockSums, int* __restrict__ blockOffs, int nb) {
    __shared__ int sdata[128];
    int tid = threadIdx.x;
    int t = (tid < nb) ? blockSums[tid] : 0;
    int x = t;
    sdata[tid] = x; __syncthreads();
    for (int off = 1; off < 128; off <<= 1) {
        int y = (tid >= off) ? sdata[tid - off] : 0;
        __syncthreads();
        x += y;
        sdata[tid] = x;
        __syncthreads();
    }
    blockOffs[tid] = x - t;  // exclusive
}

__global__ __launch_bounds__(256) void k_scan3(int* __restrict__ row_ptr, const int* __restrict__ blockOffs, int n) {
    int add = blockOffs[blockIdx.x];
    int base = blockIdx.x * 1024 + threadIdx.x * 4;
    if (base + 0 < n) row_ptr[base + 0] += add;
    if (base + 1 < n) row_ptr[base + 1] += add;
    if (base + 2 < n) row_ptr[base + 2] += add;
    if (base + 3 < n) row_ptr[base + 3] += add;
}

// One atomic + one 8B write per edge. row_head starts as a copy of row_ptr.
__global__ __launch_bounds__(256) void k_fill2(const int* __restrict__ ei, int* __restrict__ row_head,
                                               int2* __restrict__ csr2, int E) {
    int e = blockIdx.x * 256 + threadIdx.x;
    if (e >= E) return;
    int s = ei[e];
    int d = ei[E + e];
    int p = atomicAdd(&row_head[d], 1);
    csr2[p] = make_int2(s, e);
}

// agg_e[v] = sum of edge_attr over incoming edges. No atomics.
__global__ __launch_bounds__(256) void k_agge(const int2* __restrict__ csr2, const float* __restrict__ ea,
                                              const int* __restrict__ row_ptr, const int* __restrict__ cnt,
                                              float* __restrict__ agg_e, int n) {
    int v = blockIdx.x * 256 + threadIdx.x;
    if (v >= n) return;
    int start = row_ptr[v];
    int deg = cnt[v];
    float4 a = make_float4(0.f, 0.f, 0.f, 0.f);
    for (int i = 0; i < deg; ++i) {
        int eid = csr2[start + i].y;
        float4 t = ((const float4*)ea)[eid];
        a.x += t.x; a.y += t.y; a.z += t.z; a.w += t.w;
    }
    ((float4*)agg_e)[v] = a;
}

// ---------------- one-time conversions ----------------
__global__ __launch_bounds__(256) void k_cvt(const float* __restrict__ in, ushort* __restrict__ out, int total4) {
    int i = blockIdx.x * 256 + threadIdx.x;
    if (i >= total4) return;
    float4 v = ((const float4*)in)[i];
    unsigned lo = (unsigned)f2bf(v.x) | ((unsigned)f2bf(v.y) << 16);
    unsigned hi = (unsigned)f2bf(v.z) | ((unsigned)f2bf(v.w) << 16);
    ((uint2*)out)[i] = make_uint2(lo, hi);
}

// Wt[n][k] = bf16(W[k][n]) for the 128x128 node-feature part of W (k-major -> n-major)
__global__ __launch_bounds__(256) void k_cvtW(const float* __restrict__ W, ushort* __restrict__ Wt) {
    int i = blockIdx.x * 256 + threadIdx.x;
    if (i >= 16384) return;
    int nn = i & 127, kk = i >> 7;
    Wt[nn * 128 + kk] = f2bf(W[kk * 128 + nn]);
}

// ---------------- per-layer: gather aggregation (bf16 rows, fp32 accum) ----------------
__global__ __launch_bounds__(256) void k_gather_b(const ushort* __restrict__ xb, ushort* __restrict__ aggb,
                                                  const int* __restrict__ row_ptr, const int* __restrict__ cnt,
                                                  const int2* __restrict__ csr2, int n) {
    int wid = (blockIdx.x * 256 + threadIdx.x) >> 6;
    int lane = threadIdx.x & 63;
    if (wid >= n) return;
    const unsigned* x2 = (const unsigned*)xb;  // 2 bf16 per uint
    unsigned self = x2[(size_t)wid * 64 + lane];
    float ax = bf2f((ushort)(self & 0xffffu));
    float ay = bf2f((ushort)(self >> 16));
    int start = row_ptr[wid];
    int deg = cnt[wid];
    for (int base = 0; base < deg; base += 64) {
        int idx = 0;
        if (base + lane < deg) idx = csr2[start + base + lane].x;
        int m = deg - base; if (m > 64) m = 64;
        for (int i = 0; i < m; ++i) {
            int s = __shfl(idx, i);
            unsigned xv = x2[(size_t)s * 64 + lane];
            ax += bf2f((ushort)(xv & 0xffffu));
            ay += bf2f((ushort)(xv >> 16));
        }
    }
    ((unsigned*)aggb)[(size_t)wid * 64 + lane] = (unsigned)f2bf(ax) | ((unsigned)f2bf(ay) << 16);
}

// ---------------- per-layer: MFMA GEMM + edge-bias + bias + relu ----------------
// xb_out[v,:] = bf16( relu( aggb[v,:] @ W[0:128,:] + agg_e[v,:] @ W[128:132,:] + b ) )
// A-frag (16x16x32): lane l -> A[row = l&15][k = (l>>4)*8 + j], j=0..7  (16B contiguous)
// B-frag:            lane l -> B[k = (l>>4)*8 + j][col = l&15]  -> from Wt[n][k]: 16B contiguous
// D:                 lane l, reg r -> D[row = (l>>4)*4 + r][col = l&15]   (m89-verified)
__global__ __launch_bounds__(256) void k_gemm_mfma(const ushort* __restrict__ aggb, ushort* __restrict__ xb_out,
                                                   const float* __restrict__ agg_e, const ushort* __restrict__ Wt,
                                                   const float* __restrict__ W, const float* __restrict__ bias, int n) {
    __shared__ float we[512];
    __shared__ float bl[128];
    int tid = threadIdx.x;
    for (int i = tid; i < 512; i += 256) we[i] = W[128 * 128 + i];
    if (tid < 128) bl[tid] = bias[tid];
    __syncthreads();

    int wave = tid >> 6, lane = tid & 63;
    int r16 = lane & 15;
    int kc = (lane >> 4) * 8;
    int row0 = blockIdx.x * 64 + wave * 16;

    int arr = row0 + r16;
    const ushort* arow = aggb + (size_t)(arr < n ? arr : (n - 1)) * 128 + kc;

    f32x4 acc[8];
#pragma unroll
    for (int t = 0; t < 8; ++t) acc[t] = (f32x4){0.f, 0.f, 0.f, 0.f};

#pragma unroll
    for (int ks = 0; ks < 4; ++ks) {
        short8 a = *(const short8*)(arow + ks * 32);
#pragma unroll
        for (int nt = 0; nt < 8; ++nt) {
            short8 b = *(const short8*)(Wt + (size_t)(nt * 16 + r16) * 128 + ks * 32 + kc);
            acc[nt] = __builtin_amdgcn_mfma_f32_16x16x32_bf16(a, b, acc[nt], 0, 0, 0);
        }
    }

    // epilogue: D row = (lane>>4)*4 + r, col = nt*16 + r16
#pragma unroll
    for (int r = 0; r < 4; ++r) {
        int row = row0 + (lane >> 4) * 4 + r;
        if (row >= n) continue;
        float4 e = *(const float4*)(agg_e + (size_t)row * 4);
#pragma unroll
        for (int nt = 0; nt < 8; ++nt) {
            int col = nt * 16 + r16;
            float o = acc[nt][r] + bl[col] + e.x * we[col] + e.y * we[128 + col]
                    + e.z * we[256 + col] + e.w * we[384 + col];
            o = fmaxf(o, 0.f);
            xb_out[(size_t)row * 128 + col] = f2bf(o);
        }
    }
}

// ---------------- pooling (segmented: batch is sorted) ----------------

__global__ __launch_bounds__(256) void k_bounds(const int* __restrict__ batch, int* __restrict__ gstart,
                                                int n, int G) {
    int i = blockIdx.x * 256 + threadIdx.x;
    if (i >= n) return;
    int g = batch[i];
    if (i == 0) {
        for (int q = 0; q <= g; ++q) gstart[q] = 0;
    } else {
        int gp = batch[i - 1];
        for (int q = gp + 1; q <= g; ++q) gstart[q] = i;
    }
    if (i == n - 1) {
        for (int q = g + 1; q <= G; ++q) gstart[q] = n;
    }
}

#define POOL_S 16
__global__ __launch_bounds__(128) void k_pool2(const ushort* __restrict__ xb, const int* __restrict__ gstart,
                                               float* __restrict__ pooled) {
    int g = blockIdx.x / POOL_S;
    int s = blockIdx.x % POOL_S;
    int t = threadIdx.x;
    int lo = gstart[g], hi = gstart[g + 1];
    int len = hi - lo;
    if (len <= 0) return;
    int chunk = (len + POOL_S - 1) / POOL_S;
    int a = lo + s * chunk;
    int b = a + chunk; if (b > hi) b = hi;
    if (a >= b) return;
    float acc = 0.f;
    for (int v = a; v < b; ++v) acc += bf2f(xb[(size_t)v * 128 + t]);
    atomicAdd(&pooled[g * 128 + t], acc);
}

__global__ __launch_bounds__(128) void k_final(const float* __restrict__ pooled, const int* __restrict__ gstart,
                                               const float* __restrict__ Wout, const float* __restrict__ bout,
                                               float* __restrict__ out, int G) {
    int g = threadIdx.x;
    if (g >= G) return;
    float c = (float)(gstart[g + 1] - gstart[g]);
    if (c < 1.f) c = 1.f;
    float l0 = bout[0], l1 = bout[1], l2 = bout[2], l3 = bout[3];
    for (int k = 0; k < 128; ++k) {
        float p = pooled[g * 128 + k] / c;
        l0 += p * Wout[k * 4 + 0];
        l1 += p * Wout[k * 4 + 1];
        l2 += p * Wout[k * 4 + 2];
        l3 += p * Wout[k * 4 + 3];
    }
    float m = fmaxf(fmaxf(l0, l1), fmaxf(l2, l3));
    float s = expf(l0 - m) + expf(l1 - m) + expf(l2 - m) + expf(l3 - m);
    float ls = logf(s);
    out[g * 4 + 0] = l0 - m - ls;
    out[g * 4 + 1] = l1 - m - ls;
    out[g * 4 + 2] = l2 - m - ls;
    out[g * 4 + 3] = l3 - m - ls;
}

extern "C" void kernel_launch(void* const* d_in, const int* in_sizes, int n_in,
                              void* d_out, int out_size, void* d_ws, size_t ws_size,
                              hipStream_t stream) {
    const float* x    = (const float*)d_in[0];
    const int*   ei   = (const int*)d_in[1];
    const float* ea   = (const float*)d_in[2];
    const int*   bat  = (const int*)d_in[3];
    const float* W0   = (const float*)d_in[4];
    const float* b0   = (const float*)d_in[5];
    const float* W1   = (const float*)d_in[6];
    const float* b1   = (const float*)d_in[7];
    const float* W2   = (const float*)d_in[8];
    const float* b2   = (const float*)d_in[9];
    const float* Wout = (const float*)d_in[10];
    const float* bout = (const float*)d_in[11];
    float* out = (float*)d_out;

    int n = in_sizes[0] / 128;
    int E = in_sizes[1] / 2;
    int G = out_size / 4;

    char* w = (char*)d_ws;
    int* cnt       = (int*)w; w += (size_t)n * 4;
    int* row_head  = (int*)w; w += (size_t)n * 4;
    int* row_ptr   = (int*)w; w += (size_t)n * 4;
    int* blockSums = (int*)w; w += 4096;
    int* blockOffs = (int*)w; w += 4096;
    int2* csr2     = (int2*)w; w += (size_t)E * 8;
    float* agg_e   = (float*)w; w += (size_t)n * 16;
    float* pooled  = (float*)w; w += (size_t)G * 128 * 4;
    int* gstart    = (int*)w; w += (size_t)(G + 4) * 4;
    ushort* xb     = (ushort*)w; w += (size_t)n * 128 * 2;
    ushort* aggb   = (ushort*)w; w += (size_t)n * 128 * 2;
    ushort* Wt0    = (ushort*)w; w += 128 * 128 * 2;
    ushort* Wt1    = (ushort*)w; w += 128 * 128 * 2;
    ushort* Wt2    = (ushort*)w; w += 128 * 128 * 2;

    hipMemsetAsync(cnt, 0, (size_t)n * 4, stream);
    hipMemsetAsync(pooled, 0, (size_t)G * 128 * 4, stream);

    int eb = (E + 255) / 256;
    int nb = (n + 1023) / 1024;   // 98 for n=100000, fits k_scan2's 128 slots
    k_count<<<eb, 256, 0, stream>>>(ei, cnt, E);
    k_scan1<<<nb, 256, 0, stream>>>(cnt, row_ptr, blockSums, n);
    k_scan2<<<1, 128, 0, stream>>>(blockSums, blockOffs, nb);
    k_scan3<<<nb, 256, 0, stream>>>(row_ptr, blockOffs, n);
    hipMemcpyAsync(row_head, row_ptr, (size_t)n * 4, hipMemcpyDeviceToDevice, stream);
    k_fill2<<<eb, 256, 0, stream>>>(ei, row_head, csr2, E);
    k_agge<<<(n + 255) / 256, 256, 0, stream>>>(csr2, ea, row_ptr, cnt, agg_e, n);
    k_bounds<<<(n + 255) / 256, 256, 0, stream>>>(bat, gstart, n, G);
    k_cvt<<<(n * 32 + 255) / 256, 256, 0, stream>>>(x, xb, n * 32);  // n*128/4 items
    k_cvtW<<<64, 256, 0, stream>>>(W0, Wt0);
    k_cvtW<<<64, 256, 0, stream>>>(W1, Wt1);
    k_cvtW<<<64, 256, 0, stream>>>(W2, Wt2);

    int gb = (n + 3) / 4;     // 4 waves/block, wave per node
    int mb = (n + 63) / 64;   // 64 rows per GEMM block

    k_gather_b<<<gb, 256, 0, stream>>>(xb, aggb, row_ptr, cnt, csr2, n);
    k_gemm_mfma<<<mb, 256, 0, stream>>>(aggb, xb, agg_e, Wt0, W0, b0, n);
    k_gather_b<<<gb, 256, 0, stream>>>(xb, aggb, row_ptr, cnt, csr2, n);
    k_gemm_mfma<<<mb, 256, 0, stream>>>(aggb, xb, agg_e, Wt1, W1, b1, n);
    k_gather_b<<<gb, 256, 0, stream>>>(xb, aggb, row_ptr, cnt, csr2, n);
    k_gemm_mfma<<<mb, 256, 0, stream>>>(aggb, xb, agg_e, Wt2, W2, b2, n);

    k_pool2<<<G * POOL_S, 128, 0, stream>>>(xb, gstart, pooled);
    k_final<<<1, 128, 0, stream>>>(pooled, gstart, Wout, bout, out, G);
}

// Round 6
// 537.899 us; speedup vs baseline: 3.0440x; 1.3690x over previous
//
#include <hip/hip_runtime.h>

typedef __attribute__((ext_vector_type(8))) short short8;
typedef __attribute__((ext_vector_type(4))) float f32x4;

// ---------------- bf16 helpers ----------------
__device__ inline ushort f2bf(float f) {
    unsigned u = __float_as_uint(f);
    u += 0x7fffu + ((u >> 16) & 1u);   // round-to-nearest-even
    return (ushort)(u >> 16);
}
__device__ inline float bf2f(ushort h) { return __uint_as_float(((unsigned)h) << 16); }

// ---------------- CSR build ----------------

__global__ __launch_bounds__(256) void k_count(const int* __restrict__ ei, int* __restrict__ cnt, int E) {
    int e = blockIdx.x * 256 + threadIdx.x;
    if (e < E) atomicAdd(&cnt[ei[E + e]], 1);
}

__global__ __launch_bounds__(256) void k_scan1(const int* __restrict__ cnt, int* __restrict__ row_ptr,
                                               int* __restrict__ blockSums, int n) {
    __shared__ int sdata[256];
    int tid = threadIdx.x;
    int base = blockIdx.x * 1024 + tid * 4;
    int v0 = (base + 0 < n) ? cnt[base + 0] : 0;
    int v1 = (base + 1 < n) ? cnt[base + 1] : 0;
    int v2 = (base + 2 < n) ? cnt[base + 2] : 0;
    int v3 = (base + 3 < n) ? cnt[base + 3] : 0;
    int t = v0 + v1 + v2 + v3;
    int x = t;
    sdata[tid] = x; __syncthreads();
    for (int off = 1; off < 256; off <<= 1) {
        int y = (tid >= off) ? sdata[tid - off] : 0;
        __syncthreads();
        x += y;
        sdata[tid] = x;
        __syncthreads();
    }
    int p = x - t;  // exclusive prefix within block
    if (base + 0 < n) row_ptr[base + 0] = p;
    if (base + 1 < n) row_ptr[base + 1] = p + v0;
    if (base + 2 < n) row_ptr[base + 2] = p + v0 + v1;
    if (base + 3 < n) row_ptr[base + 3] = p + v0 + v1 + v2;
    if (tid == 255) blockSums[blockIdx.x] = x;
}

__global__ __launch_bounds__(128) void k_scan2(const int* __restrict__ blockSums, int* __restrict__ blockOffs, int nb) {
    __shared__ int sdata[128];
    int tid = threadIdx.x;
    int t = (tid < nb) ? blockSums[tid] : 0;
    int x = t;
    sdata[tid] = x; __syncthreads();
    for (int off = 1; off < 128; off <<= 1) {
        int y = (tid >= off) ? sdata[tid - off] : 0;
        __syncthreads();
        x += y;
        sdata[tid] = x;
        __syncthreads();
    }
    blockOffs[tid] = x - t;  // exclusive
}

__global__ __launch_bounds__(256) void k_scan3(int* __restrict__ row_ptr, const int* __restrict__ blockOffs, int n) {
    int add = blockOffs[blockIdx.x];
    int base = blockIdx.x * 1024 + threadIdx.x * 4;
    if (base + 0 < n) row_ptr[base + 0] += add;
    if (base + 1 < n) row_ptr[base + 1] += add;
    if (base + 2 < n) row_ptr[base + 2] += add;
    if (base + 3 < n) row_ptr[base + 3] += add;
}

// bucket_head[b] = CSR offset of first node in bucket b (512 nodes per bucket)
__global__ __launch_bounds__(256) void k_bhead(const int* __restrict__ row_ptr, int* __restrict__ bucket_head,
                                               int n, int E, int nbuck) {
    int b = threadIdx.x;
    if (b >= nbuck) return;
    int v = b << 9;
    bucket_head[b] = (v < n) ? row_ptr[v] : E;
}

// Pass A: bin edges by dst bucket. Per-block LDS histogram + one global
// reservation per (block,bucket) -> coalesced contiguous writes per run.
__global__ __launch_bounds__(256) void k_binA(const int* __restrict__ ei, int* __restrict__ bucket_head,
                                              int2* __restrict__ tmp8, int* __restrict__ tmpd, int E) {
    __shared__ int hist[256], base[256], fill[256];
    int tid = threadIdx.x;
    hist[tid] = 0; fill[tid] = 0;
    __syncthreads();
    int e0 = blockIdx.x * 4096;
    int d[16];
#pragma unroll
    for (int k = 0; k < 16; ++k) {
        int e = e0 + k * 256 + tid;
        d[k] = -1;
        if (e < E) { d[k] = ei[E + e]; atomicAdd(&hist[d[k] >> 9], 1); }
    }
    __syncthreads();
    if (hist[tid]) base[tid] = atomicAdd(&bucket_head[tid], hist[tid]);
    __syncthreads();
#pragma unroll
    for (int k = 0; k < 16; ++k) {
        if (d[k] >= 0) {
            int e = e0 + k * 256 + tid;
            int b = d[k] >> 9;
            int p = base[b] + atomicAdd(&fill[b], 1);
            tmp8[p] = make_int2(ei[e], e);
            tmpd[p] = d[k];
        }
    }
}

// Pass B: one block per bucket; LDS per-node heads; scatter confined to a
// 64KB window owned by this block -> write-back once per line.
__global__ __launch_bounds__(256) void k_binB(const int2* __restrict__ tmp8, const int* __restrict__ tmpd,
                                              const int* __restrict__ row_ptr, int2* __restrict__ csr2,
                                              int n, int E) {
    __shared__ int lhead[512];
    int b = blockIdx.x;
    int lo = b << 9;
    int hi = lo + 512; if (hi > n) hi = n;
    int tid = threadIdx.x;
    for (int i = tid; i < hi - lo; i += 256) lhead[i] = row_ptr[lo + i];
    __syncthreads();
    int jlo = row_ptr[lo];
    int jhi = (hi < n) ? row_ptr[hi] : E;
    for (int j = jlo + tid; j < jhi; j += 256) {
        int dd = tmpd[j];
        int2 se = tmp8[j];
        int pos = atomicAdd(&lhead[dd - lo], 1);
        csr2[pos] = se;
    }
}

// agg_e[v] = sum of edge_attr over incoming edges. No atomics.
__global__ __launch_bounds__(256) void k_agge(const int2* __restrict__ csr2, const float* __restrict__ ea,
                                              const int* __restrict__ row_ptr, const int* __restrict__ cnt,
                                              float* __restrict__ agg_e, int n) {
    int v = blockIdx.x * 256 + threadIdx.x;
    if (v >= n) return;
    int start = row_ptr[v];
    int deg = cnt[v];
    float4 a = make_float4(0.f, 0.f, 0.f, 0.f);
    for (int i = 0; i < deg; ++i) {
        int eid = csr2[start + i].y;
        float4 t = ((const float4*)ea)[eid];
        a.x += t.x; a.y += t.y; a.z += t.z; a.w += t.w;
    }
    ((float4*)agg_e)[v] = a;
}

// ---------------- one-time conversions ----------------
__global__ __launch_bounds__(256) void k_cvt(const float* __restrict__ in, ushort* __restrict__ out, int total4) {
    int i = blockIdx.x * 256 + threadIdx.x;
    if (i >= total4) return;
    float4 v = ((const float4*)in)[i];
    unsigned lo = (unsigned)f2bf(v.x) | ((unsigned)f2bf(v.y) << 16);
    unsigned hi = (unsigned)f2bf(v.z) | ((unsigned)f2bf(v.w) << 16);
    ((uint2*)out)[i] = make_uint2(lo, hi);
}

// Wt[n][k] = bf16(W[k][n]) for the 128x128 node-feature part of W
__global__ __launch_bounds__(256) void k_cvtW(const float* __restrict__ W, ushort* __restrict__ Wt) {
    int i = blockIdx.x * 256 + threadIdx.x;
    if (i >= 16384) return;
    int nn = i & 127, kk = i >> 7;
    Wt[nn * 128 + kk] = f2bf(W[kk * 128 + nn]);
}

// ---------------- per-layer: gather aggregation ----------------
// Wave per node; 4 groups of 16 lanes; each group handles every 4th edge,
// lane loads uint4 (16B) -> 4 rows in flight, 4x fewer load instructions.
__global__ __launch_bounds__(256) void k_gather_b(const ushort* __restrict__ xb, ushort* __restrict__ aggb,
                                                  const int* __restrict__ row_ptr, const int* __restrict__ cnt,
                                                  const int2* __restrict__ csr2, int n) {
    int wid = (blockIdx.x * 256 + threadIdx.x) >> 6;
    int lane = threadIdx.x & 63;
    if (wid >= n) return;
    int g = lane >> 4, t = lane & 15;
    const uint4* x4 = (const uint4*)xb;   // row = 16 uint4
    float acc[8];
    {
        uint4 v = make_uint4(0u, 0u, 0u, 0u);
        if (g == 0) v = x4[(size_t)wid * 16 + t];  // self loop
        acc[0] = bf2f((ushort)(v.x & 0xffffu)); acc[1] = bf2f((ushort)(v.x >> 16));
        acc[2] = bf2f((ushort)(v.y & 0xffffu)); acc[3] = bf2f((ushort)(v.y >> 16));
        acc[4] = bf2f((ushort)(v.z & 0xffffu)); acc[5] = bf2f((ushort)(v.z >> 16));
        acc[6] = bf2f((ushort)(v.w & 0xffffu)); acc[7] = bf2f((ushort)(v.w >> 16));
    }
    int start = row_ptr[wid];
    int deg = cnt[wid];
    for (int i = g; i < deg; i += 4) {
        int s = csr2[start + i].x;          // same addr across 16 lanes -> broadcast
        uint4 v = x4[(size_t)s * 16 + t];
        acc[0] += bf2f((ushort)(v.x & 0xffffu)); acc[1] += bf2f((ushort)(v.x >> 16));
        acc[2] += bf2f((ushort)(v.y & 0xffffu)); acc[3] += bf2f((ushort)(v.y >> 16));
        acc[4] += bf2f((ushort)(v.z & 0xffffu)); acc[5] += bf2f((ushort)(v.z >> 16));
        acc[6] += bf2f((ushort)(v.w & 0xffffu)); acc[7] += bf2f((ushort)(v.w >> 16));
    }
#pragma unroll
    for (int j = 0; j < 8; ++j) {
        acc[j] += __shfl_xor(acc[j], 16);
        acc[j] += __shfl_xor(acc[j], 32);
    }
    if (lane < 16) {
        uint4 o;
        o.x = (unsigned)f2bf(acc[0]) | ((unsigned)f2bf(acc[1]) << 16);
        o.y = (unsigned)f2bf(acc[2]) | ((unsigned)f2bf(acc[3]) << 16);
        o.z = (unsigned)f2bf(acc[4]) | ((unsigned)f2bf(acc[5]) << 16);
        o.w = (unsigned)f2bf(acc[6]) | ((unsigned)f2bf(acc[7]) << 16);
        *(uint4*)(aggb + (size_t)wid * 128 + lane * 8) = o;
    }
}

// ---------------- per-layer: MFMA GEMM + edge-bias + bias + relu ----------------
__global__ __launch_bounds__(256) void k_gemm_mfma(const ushort* __restrict__ aggb, ushort* __restrict__ xb_out,
                                                   const float* __restrict__ agg_e, const ushort* __restrict__ Wt,
                                                   const float* __restrict__ W, const float* __restrict__ bias, int n) {
    __shared__ float we[512];
    __shared__ float bl[128];
    int tid = threadIdx.x;
    for (int i = tid; i < 512; i += 256) we[i] = W[128 * 128 + i];
    if (tid < 128) bl[tid] = bias[tid];
    __syncthreads();

    int wave = tid >> 6, lane = tid & 63;
    int r16 = lane & 15;
    int kc = (lane >> 4) * 8;
    int row0 = blockIdx.x * 64 + wave * 16;

    int arr = row0 + r16;
    const ushort* arow = aggb + (size_t)(arr < n ? arr : (n - 1)) * 128 + kc;

    f32x4 acc[8];
#pragma unroll
    for (int t = 0; t < 8; ++t) acc[t] = (f32x4){0.f, 0.f, 0.f, 0.f};

#pragma unroll
    for (int ks = 0; ks < 4; ++ks) {
        short8 a = *(const short8*)(arow + ks * 32);
#pragma unroll
        for (int nt = 0; nt < 8; ++nt) {
            short8 b = *(const short8*)(Wt + (size_t)(nt * 16 + r16) * 128 + ks * 32 + kc);
            acc[nt] = __builtin_amdgcn_mfma_f32_16x16x32_bf16(a, b, acc[nt], 0, 0, 0);
        }
    }

#pragma unroll
    for (int r = 0; r < 4; ++r) {
        int row = row0 + (lane >> 4) * 4 + r;
        if (row >= n) continue;
        float4 e = *(const float4*)(agg_e + (size_t)row * 4);
#pragma unroll
        for (int nt = 0; nt < 8; ++nt) {
            int col = nt * 16 + r16;
            float o = acc[nt][r] + bl[col] + e.x * we[col] + e.y * we[128 + col]
                    + e.z * we[256 + col] + e.w * we[384 + col];
            o = fmaxf(o, 0.f);
            xb_out[(size_t)row * 128 + col] = f2bf(o);
        }
    }
}

// ---------------- pooling (segmented: batch is sorted) ----------------

__global__ __launch_bounds__(256) void k_bounds(const int* __restrict__ batch, int* __restrict__ gstart,
                                                int n, int G) {
    int i = blockIdx.x * 256 + threadIdx.x;
    if (i >= n) return;
    int g = batch[i];
    if (i == 0) {
        for (int q = 0; q <= g; ++q) gstart[q] = 0;
    } else {
        int gp = batch[i - 1];
        for (int q = gp + 1; q <= g; ++q) gstart[q] = i;
    }
    if (i == n - 1) {
        for (int q = g + 1; q <= G; ++q) gstart[q] = n;
    }
}

#define POOL_S 16
__global__ __launch_bounds__(128) void k_pool2(const ushort* __restrict__ xb, const int* __restrict__ gstart,
                                               float* __restrict__ pooled) {
    int g = blockIdx.x / POOL_S;
    int s = blockIdx.x % POOL_S;
    int t = threadIdx.x;
    int lo = gstart[g], hi = gstart[g + 1];
    int len = hi - lo;
    if (len <= 0) return;
    int chunk = (len + POOL_S - 1) / POOL_S;
    int a = lo + s * chunk;
    int b = a + chunk; if (b > hi) b = hi;
    if (a >= b) return;
    float acc = 0.f;
    for (int v = a; v < b; ++v) acc += bf2f(xb[(size_t)v * 128 + t]);
    atomicAdd(&pooled[g * 128 + t], acc);
}

__global__ __launch_bounds__(128) void k_final(const float* __restrict__ pooled, const int* __restrict__ gstart,
                                               const float* __restrict__ Wout, const float* __restrict__ bout,
                                               float* __restrict__ out, int G) {
    int g = threadIdx.x;
    if (g >= G) return;
    float c = (float)(gstart[g + 1] - gstart[g]);
    if (c < 1.f) c = 1.f;
    float l0 = bout[0], l1 = bout[1], l2 = bout[2], l3 = bout[3];
    for (int k = 0; k < 128; ++k) {
        float p = pooled[g * 128 + k] / c;
        l0 += p * Wout[k * 4 + 0];
        l1 += p * Wout[k * 4 + 1];
        l2 += p * Wout[k * 4 + 2];
        l3 += p * Wout[k * 4 + 3];
    }
    float m = fmaxf(fmaxf(l0, l1), fmaxf(l2, l3));
    float s = expf(l0 - m) + expf(l1 - m) + expf(l2 - m) + expf(l3 - m);
    float ls = logf(s);
    out[g * 4 + 0] = l0 - m - ls;
    out[g * 4 + 1] = l1 - m - ls;
    out[g * 4 + 2] = l2 - m - ls;
    out[g * 4 + 3] = l3 - m - ls;
}

extern "C" void kernel_launch(void* const* d_in, const int* in_sizes, int n_in,
                              void* d_out, int out_size, void* d_ws, size_t ws_size,
                              hipStream_t stream) {
    const float* x    = (const float*)d_in[0];
    const int*   ei   = (const int*)d_in[1];
    const float* ea   = (const float*)d_in[2];
    const int*   bat  = (const int*)d_in[3];
    const float* W0   = (const float*)d_in[4];
    const float* b0   = (const float*)d_in[5];
    const float* W1   = (const float*)d_in[6];
    const float* b1   = (const float*)d_in[7];
    const float* W2   = (const float*)d_in[8];
    const float* b2   = (const float*)d_in[9];
    const float* Wout = (const float*)d_in[10];
    const float* bout = (const float*)d_in[11];
    float* out = (float*)d_out;

    int n = in_sizes[0] / 128;
    int E = in_sizes[1] / 2;
    int G = out_size / 4;
    int nbuck = (n + 511) >> 9;   // 196 for n=100000 (max 256 supported)

    char* w = (char*)d_ws;
    auto alloc = [&](size_t bytes) { char* p = w; w += (bytes + 255) & ~(size_t)255; return p; };
    int* cnt         = (int*)alloc((size_t)n * 4);
    int* row_ptr     = (int*)alloc((size_t)n * 4);
    int* blockSums   = (int*)alloc(4096);
    int* blockOffs   = (int*)alloc(4096);
    int* bucket_head = (int*)alloc(1024);
    int2* csr2       = (int2*)alloc((size_t)E * 8);
    int2* tmp8       = (int2*)alloc((size_t)E * 8);
    int* tmpd        = (int*)alloc((size_t)E * 4);
    float* agg_e     = (float*)alloc((size_t)n * 16);
    float* pooled    = (float*)alloc((size_t)G * 128 * 4);
    int* gstart      = (int*)alloc((size_t)(G + 4) * 4);
    ushort* xb       = (ushort*)alloc((size_t)n * 128 * 2);
    ushort* aggb     = (ushort*)alloc((size_t)n * 128 * 2);
    ushort* Wt0      = (ushort*)alloc(128 * 128 * 2);
    ushort* Wt1      = (ushort*)alloc(128 * 128 * 2);
    ushort* Wt2      = (ushort*)alloc(128 * 128 * 2);

    hipMemsetAsync(cnt, 0, (size_t)n * 4, stream);
    hipMemsetAsync(pooled, 0, (size_t)G * 128 * 4, stream);

    int eb = (E + 255) / 256;
    int nb = (n + 1023) / 1024;   // 98 for n=100000, fits k_scan2's 128 slots
    k_count<<<eb, 256, 0, stream>>>(ei, cnt, E);
    k_scan1<<<nb, 256, 0, stream>>>(cnt, row_ptr, blockSums, n);
    k_scan2<<<1, 128, 0, stream>>>(blockSums, blockOffs, nb);
    k_scan3<<<nb, 256, 0, stream>>>(row_ptr, blockOffs, n);
    k_bhead<<<1, 256, 0, stream>>>(row_ptr, bucket_head, n, E, nbuck);
    k_binA<<<(E + 4095) / 4096, 256, 0, stream>>>(ei, bucket_head, tmp8, tmpd, E);
    k_binB<<<nbuck, 256, 0, stream>>>(tmp8, tmpd, row_ptr, csr2, n, E);
    k_agge<<<(n + 255) / 256, 256, 0, stream>>>(csr2, ea, row_ptr, cnt, agg_e, n);
    k_bounds<<<(n + 255) / 256, 256, 0, stream>>>(bat, gstart, n, G);
    k_cvt<<<(n * 32 + 255) / 256, 256, 0, stream>>>(x, xb, n * 32);
    k_cvtW<<<64, 256, 0, stream>>>(W0, Wt0);
    k_cvtW<<<64, 256, 0, stream>>>(W1, Wt1);
    k_cvtW<<<64, 256, 0, stream>>>(W2, Wt2);

    int gb = (n + 3) / 4;     // 4 waves/block, wave per node
    int mb = (n + 63) / 64;   // 64 rows per GEMM block

    k_gather_b<<<gb, 256, 0, stream>>>(xb, aggb, row_ptr, cnt, csr2, n);
    k_gemm_mfma<<<mb, 256, 0, stream>>>(aggb, xb, agg_e, Wt0, W0, b0, n);
    k_gather_b<<<gb, 256, 0, stream>>>(xb, aggb, row_ptr, cnt, csr2, n);
    k_gemm_mfma<<<mb, 256, 0, stream>>>(aggb, xb, agg_e, Wt1, W1, b1, n);
    k_gather_b<<<gb, 256, 0, stream>>>(xb, aggb, row_ptr, cnt, csr2, n);
    k_gemm_mfma<<<mb, 256, 0, stream>>>(aggb, xb, agg_e, Wt2, W2, b2, n);

    k_pool2<<<G * POOL_S, 128, 0, stream>>>(xb, gstart, pooled);
    k_final<<<1, 128, 0, stream>>>(pooled, gstart, Wout, bout, out, G);
}